// Round 6
// baseline (334.072 us; speedup 1.0000x reference)
//
#include <hip/hip_runtime.h>
#include <cstdint>
#include <cstddef>

// ---------------------------------------------------------------------------
// MultiheadSelectiveAttention (B=2, S=2048, D=1024, H=16, dh=64), fp32 in/out.
//   k_cast_all: X,Wq,Wk -> hi/lo bf16; Wv,Wo -> bf16 (one launch)
//   k_mega: qk GEMM (512 blk) + head0 corr->Dlt (128 blk) + V^T GEMM (512 blk)
//   k_ln_pack2: LN(Q),LN(K); head-0 cols += Dlt -> bf16 packs (+head0 lo)
//   k_s0: head-0 scores (3-pass split) + fused segment column sums
//   k_seg_apply: in-place S -> -F*log2e (prefix from seg sums)
//   k_attn: 128-row Q tiles, fixed-max softmax, dbuf DMA staging, register P
//           __launch_bounds__(256,2): grid=512=2 blk/CU; 256-VGPR cap, no spill
//   k_gemm_nt64: out = Obf @ Wo^T
// ---------------------------------------------------------------------------

typedef unsigned short u16;
typedef __attribute__((ext_vector_type(8))) __bf16 bf16x8;
typedef __attribute__((ext_vector_type(4))) float f32x4;

#define D_MODEL 1024
#define N_HEADS 16
#define BATCH   2
#define SEQ     2048
#define D_HEAD  64
#define ROWS    (BATCH*SEQ)   /* 4096 */
#define NSEG    16
#define SEGLEN  128
#define LOG2E   1.44269504f

static __device__ __forceinline__ u16 f2bf(float f){
  union { float f; uint32_t u; } v; v.f = f;
  uint32_t r = v.u + 0x7fffu + ((v.u >> 16) & 1u);
  return (u16)(r >> 16);
}
static __device__ __forceinline__ float bf2f(u16 h){
  union { uint32_t u; float f; } v; v.u = ((uint32_t)h) << 16;
  return v.f;
}
// round-half-up bf16 pair pack (cheap: 2 adds + merge)
static __device__ __forceinline__ uint32_t pack2(float a, float b){
  uint32_t ua = __float_as_uint(a) + 0x8000u;
  uint32_t ub = __float_as_uint(b) + 0x8000u;
  return (ua >> 16) | (ub & 0xffff0000u);
}

// ------------------------- merged cast kernel ------------------------------
__global__ void k_cast_all(const float* __restrict__ X,
                           u16* __restrict__ Xhi, u16* __restrict__ Xlo,
                           const float* __restrict__ Wq,
                           u16* __restrict__ Wqh, u16* __restrict__ Wql,
                           const float* __restrict__ Wk,
                           u16* __restrict__ Wkh, u16* __restrict__ Wkl,
                           const float* __restrict__ Wv, u16* __restrict__ Wvb,
                           const float* __restrict__ Wo, u16* __restrict__ Wob){
  int i = blockIdx.x*256 + threadIdx.x;   // float4 index
  if (i < 1572864){                       // split: X | Wq | Wk
    const float* src; u16 *dh, *dl; int base;
    if (i < 1048576){ src = X;  dh = Xhi; dl = Xlo; base = i; }
    else if (i < 1310720){ src = Wq; dh = Wqh; dl = Wql; base = i - 1048576; }
    else { src = Wk; dh = Wkh; dl = Wkl; base = i - 1310720; }
    float4 v = reinterpret_cast<const float4*>(src)[base];
    float vs[4] = {v.x, v.y, v.z, v.w};
    union { u16 s[4]; uint2 u; } uh, ul;
#pragma unroll
    for (int r=0;r<4;++r){
      uh.s[r] = f2bf(vs[r]);
      ul.s[r] = f2bf(vs[r] - bf2f(uh.s[r]));
    }
    reinterpret_cast<uint2*>(dh)[base] = uh.u;
    reinterpret_cast<uint2*>(dl)[base] = ul.u;
  } else {                                // plain: Wv | Wo
    const float* src; u16* dst; int base;
    if (i < 1835008){ src = Wv; dst = Wvb; base = i - 1572864; }
    else { src = Wo; dst = Wob; base = i - 1835008; }
    float4 v = reinterpret_cast<const float4*>(src)[base];
    float vs[4] = {v.x, v.y, v.z, v.w};
    union { u16 s[4]; uint2 u; } uh;
#pragma unroll
    for (int r=0;r<4;++r) uh.s[r] = f2bf(vs[r]);
    reinterpret_cast<uint2*>(dst)[base] = uh.u;
  }
}

// ---- mega kernel: qk (0-511) | corr->Dlt (512-639) | vt (640-1151) --------
__global__ __launch_bounds__(256) void k_mega(
    const u16* __restrict__ Xhi, const u16* __restrict__ Xlo,
    const u16* __restrict__ Wh,  const u16* __restrict__ Wl,
    const u16* __restrict__ Wvb,
    float* __restrict__ C, float* __restrict__ Dlt, u16* __restrict__ Vt)
{
  __shared__ __align__(16) u16 smem[64*136];   // 17408 B, shared by all roles
  const int bid = blockIdx.x;
  const int tid = threadIdx.x, wv = tid>>6, ln = tid&63;
  const int lane15 = ln&15, quad = ln>>4;
  const int wm = wv&1, wn = wv>>1;
  const int sRow = ln>>2, sCol = (ln&3)*8;
  f32x4 z = {0.f,0.f,0.f,0.f};

  if (bid < 512){
    // ---------------- QK projection: 128x128 tile, 1-pass ------------------
    u16* As = smem;            // 128*32
    u16* Bs = smem + 4096;     // 128*32
    const size_t rowBase = (size_t)(bid>>4)*128, colBase = (size_t)(bid&15)*128;
    f32x4 acc[4][4];
#pragma unroll
    for (int i=0;i<4;++i)
#pragma unroll
      for (int j=0;j<4;++j) acc[i][j] = z;
    for (int kt = 0; kt < 32; ++kt) {
      __syncthreads();
#pragma unroll
      for (int c = 0; c < 2; ++c) {
        int chunk = wv*2 + c;
        int r = chunk*16 + sRow;
        const u16* ga = Xhi + (rowBase + r)*1024 + kt*32 + sCol;
        const u16* gb = Wh  + (colBase + r)*1024 + kt*32 + sCol;
        __builtin_amdgcn_global_load_lds(
            (const __attribute__((address_space(1))) void*)ga,
            (__attribute__((address_space(3))) void*)(As + chunk*512), 16, 0, 0);
        __builtin_amdgcn_global_load_lds(
            (const __attribute__((address_space(1))) void*)gb,
            (__attribute__((address_space(3))) void*)(Bs + chunk*512), 16, 0, 0);
      }
      __syncthreads();
      bf16x8 af[4], bfb[4];
#pragma unroll
      for (int t=0;t<4;++t){
        af[t]  = *reinterpret_cast<const bf16x8*>(As + (wm*64 + t*16 + lane15)*32 + quad*8);
        bfb[t] = *reinterpret_cast<const bf16x8*>(Bs + (wn*64 + t*16 + lane15)*32 + quad*8);
      }
#pragma unroll
      for (int i=0;i<4;++i)
#pragma unroll
        for (int j=0;j<4;++j)
          acc[i][j] = __builtin_amdgcn_mfma_f32_16x16x32_bf16(af[i], bfb[j], acc[i][j], 0,0,0);
    }
#pragma unroll
    for (int i=0;i<4;++i){
      size_t row = rowBase + wm*64 + i*16 + quad*4;
#pragma unroll
      for (int j=0;j<4;++j){
        size_t col = colBase + wn*64 + j*16 + lane15;
#pragma unroll
        for (int r=0;r<4;++r)
          C[(row+r)*2048 + col] = acc[i][j][r];
      }
    }
  } else if (bid < 640){
    // ---- head-0 correction: Dlt = Xhi@Wlo^T + Xlo@Whi^T (per pass) --------
    u16* As = smem;            // 128*32
    u16* Bs = smem + 4096;     // 64*32
    const int idx = bid - 512;          // 0..127
    const int cx = idx & 1;             // Q / K col-group
    const int cy = (idx >> 1) & 31;     // row tile
    const int cz = idx >> 6;            // pass
    const size_t rowBase = (size_t)cy*128;
    const size_t wbase = cx ? (size_t)1024*1024 : 0;
    const u16* Ap = cz ? Xlo : Xhi;
    const u16* Bp = (cz ? Wh : Wl) + wbase;
    f32x4 acc[4][2];
#pragma unroll
    for (int i=0;i<4;++i){ acc[i][0] = z; acc[i][1] = z; }
    for (int kt = 0; kt < 32; ++kt) {
      __syncthreads();
#pragma unroll
      for (int c = 0; c < 2; ++c) {
        int chunk = wv*2 + c;
        int r = chunk*16 + sRow;
        const u16* ga = Ap + (rowBase + r)*1024 + kt*32 + sCol;
        __builtin_amdgcn_global_load_lds(
            (const __attribute__((address_space(1))) void*)ga,
            (__attribute__((address_space(3))) void*)(As + chunk*512), 16, 0, 0);
      }
      {
        int r = wv*16 + sRow;
        const u16* gb = Bp + (size_t)r*1024 + kt*32 + sCol;
        __builtin_amdgcn_global_load_lds(
            (const __attribute__((address_space(1))) void*)gb,
            (__attribute__((address_space(3))) void*)(Bs + wv*512), 16, 0, 0);
      }
      __syncthreads();
      bf16x8 af[4], bfb[2];
#pragma unroll
      for (int t=0;t<4;++t)
        af[t]  = *reinterpret_cast<const bf16x8*>(As + (wm*64 + t*16 + lane15)*32 + quad*8);
#pragma unroll
      for (int t=0;t<2;++t)
        bfb[t] = *reinterpret_cast<const bf16x8*>(Bs + (wn*32 + t*16 + lane15)*32 + quad*8);
#pragma unroll
      for (int i=0;i<4;++i)
#pragma unroll
        for (int j=0;j<2;++j)
          acc[i][j] = __builtin_amdgcn_mfma_f32_16x16x32_bf16(af[i], bfb[j], acc[i][j], 0,0,0);
    }
#pragma unroll
    for (int i=0;i<4;++i){
      size_t row = rowBase + wm*64 + i*16 + quad*4;
#pragma unroll
      for (int j=0;j<2;++j){
        size_t col = (size_t)cx*64 + wn*32 + j*16 + lane15;
#pragma unroll
        for (int r=0;r<4;++r)
          atomicAdd(&Dlt[(row+r)*128 + col], acc[i][j][r]);
      }
    }
  } else {
    // ------- V projection with fused V^T bf16 epilogue (LDS transpose) -----
    u16* As = smem;            // 128*32
    u16* Bs = smem + 4096;     // 64*32
    const int idx = bid - 640;          // 0..511
    const int bx = idx & 15, by = idx >> 4;
    const size_t rowBase = (size_t)by*128, colBase = (size_t)bx*64;
    f32x4 acc[4][2];
#pragma unroll
    for (int i=0;i<4;++i){ acc[i][0] = z; acc[i][1] = z; }
    for (int kt = 0; kt < 32; ++kt) {
      __syncthreads();
#pragma unroll
      for (int c = 0; c < 2; ++c) {
        int chunk = wv*2 + c;
        int r = chunk*16 + sRow;
        const u16* ga = Xhi + (rowBase + r)*1024 + kt*32 + sCol;
        __builtin_amdgcn_global_load_lds(
            (const __attribute__((address_space(1))) void*)ga,
            (__attribute__((address_space(3))) void*)(As + chunk*512), 16, 0, 0);
      }
      {
        int r = wv*16 + sRow;
        const u16* gb = Wvb + (colBase + r)*1024 + kt*32 + sCol;
        __builtin_amdgcn_global_load_lds(
            (const __attribute__((address_space(1))) void*)gb,
            (__attribute__((address_space(3))) void*)(Bs + wv*512), 16, 0, 0);
      }
      __syncthreads();
      bf16x8 af[4], bfb[2];
#pragma unroll
      for (int t=0;t<4;++t)
        af[t]  = *reinterpret_cast<const bf16x8*>(As + (wm*64 + t*16 + lane15)*32 + quad*8);
#pragma unroll
      for (int t=0;t<2;++t)
        bfb[t] = *reinterpret_cast<const bf16x8*>(Bs + (wn*32 + t*16 + lane15)*32 + quad*8);
#pragma unroll
      for (int i=0;i<4;++i)
#pragma unroll
        for (int j=0;j<2;++j)
          acc[i][j] = __builtin_amdgcn_mfma_f32_16x16x32_bf16(af[i], bfb[j], acc[i][j], 0,0,0);
    }
    // transpose epilogue: stage bf16 tile as [d 64][n 128] (stride 136)
    __syncthreads();
#pragma unroll
    for (int i=0;i<4;++i){
      int nl = wm*64 + i*16 + quad*4;
#pragma unroll
      for (int j=0;j<2;++j){
        int dl = wn*32 + j*16 + lane15;
#pragma unroll
        for (int r=0;r<4;++r)
          smem[dl*136 + nl + r] = f2bf(acc[i][j][r]);
      }
    }
    __syncthreads();
    const int b = by >> 4;
    const int n0 = (by & 15) * 128;
    const int bh = b*N_HEADS + bx;
    const int d = tid >> 2, seg = tid & 3;
    u16* dst = Vt + ((size_t)(bh*64 + d))*SEQ + n0 + seg*32;
    const u16* srcl = smem + d*136 + seg*32;
#pragma unroll
    for (int k=0;k<4;++k)
      *reinterpret_cast<uint4*>(dst + k*8) = *reinterpret_cast<const uint4*>(srcl + k*8);
  }
}

// --------- merged LN for Q and K + bf16 head packs (+ head0 corr) ----------
__global__ __launch_bounds__(256) void k_ln_pack2(
    const float* __restrict__ C, const float* __restrict__ Dlt,
    const float* __restrict__ gq, const float* __restrict__ bq,
    const float* __restrict__ gk, const float* __restrict__ bk,
    u16* __restrict__ Qh, u16* __restrict__ Kh,
    u16* __restrict__ Q0l, u16* __restrict__ K0l)
{
  const int row = blockIdx.x;
  const int tid = threadIdx.x;
  const float* cr = C + (size_t)row*2048;
  float4 vq = reinterpret_cast<const float4*>(cr)[tid];
  float4 vk = reinterpret_cast<const float4*>(cr)[256 + tid];
  // head-0 columns get the split-precision correction BEFORE stats
  const int h = tid >> 4;
  if (h == 0){
    float4 dq = reinterpret_cast<const float4*>(Dlt + (size_t)row*128)[tid&15];
    vq.x+=dq.x; vq.y+=dq.y; vq.z+=dq.z; vq.w+=dq.w;
  }
  if (h == 0){
    float4 dk = reinterpret_cast<const float4*>(Dlt + (size_t)row*128 + 64)[tid&15];
    vk.x+=dk.x; vk.y+=dk.y; vk.z+=dk.z; vk.w+=dk.w;
  }
  float sq  = vq.x+vq.y+vq.z+vq.w;
  float s2q = vq.x*vq.x+vq.y*vq.y+vq.z*vq.z+vq.w*vq.w;
  float sk  = vk.x+vk.y+vk.z+vk.w;
  float s2k = vk.x*vk.x+vk.y*vk.y+vk.z*vk.z+vk.w*vk.w;
#pragma unroll
  for (int o=32;o;o>>=1){
    sq += __shfl_xor(sq,o);  s2q += __shfl_xor(s2q,o);
    sk += __shfl_xor(sk,o);  s2k += __shfl_xor(s2k,o);
  }
  __shared__ float red[4][4];
  if ((tid&63)==0){
    red[tid>>6][0]=sq; red[tid>>6][1]=s2q; red[tid>>6][2]=sk; red[tid>>6][3]=s2k;
  }
  __syncthreads();
  sq  = red[0][0]+red[1][0]+red[2][0]+red[3][0];
  s2q = red[0][1]+red[1][1]+red[2][1]+red[3][1];
  sk  = red[0][2]+red[1][2]+red[2][2]+red[3][2];
  s2k = red[0][3]+red[1][3]+red[2][3]+red[3][3];
  const float muq = sq*(1.f/D_MODEL);
  const float rsq = rsqrtf(s2q*(1.f/D_MODEL) - muq*muq + 1e-5f);
  const float muk = sk*(1.f/D_MODEL);
  const float rsk = rsqrtf(s2k*(1.f/D_MODEL) - muk*muk + 1e-5f);
  const int b = row >> 11, n = row & (SEQ-1);
  const int d0 = (tid & 15)*4;
  float4 gqv = reinterpret_cast<const float4*>(gq)[tid];
  float4 bqv = reinterpret_cast<const float4*>(bq)[tid];
  float4 gkv = reinterpret_cast<const float4*>(gk)[tid];
  float4 bkv = reinterpret_cast<const float4*>(bk)[tid];
  float xq[4] = {vq.x,vq.y,vq.z,vq.w}, xk[4] = {vk.x,vk.y,vk.z,vk.w};
  float gQ[4] = {gqv.x,gqv.y,gqv.z,gqv.w}, bQ[4] = {bqv.x,bqv.y,bqv.z,bqv.w};
  float gK[4] = {gkv.x,gkv.y,gkv.z,gkv.w}, bK[4] = {bkv.x,bkv.y,bkv.z,bkv.w};
  union { u16 s[4]; uint2 u; } qh, ql, kh, kl;
#pragma unroll
  for (int r=0;r<4;++r){
    float yq = (xq[r]-muq)*rsq*gQ[r] + bQ[r];
    qh.s[r] = f2bf(yq);
    ql.s[r] = f2bf(yq - bf2f(qh.s[r]));
    float yk = (xk[r]-muk)*rsk*gK[r] + bK[r];
    kh.s[r] = f2bf(yk);
    kl.s[r] = f2bf(yk - bf2f(kh.s[r]));
  }
  size_t dst = (((size_t)(b*N_HEADS + h))*SEQ + n)*D_HEAD + d0;
  *reinterpret_cast<uint2*>(Qh + dst) = qh.u;
  *reinterpret_cast<uint2*>(Kh + dst) = kh.u;
  if (h == 0){
    size_t dl = ((size_t)b*SEQ + n)*D_HEAD + d0;
    *reinterpret_cast<uint2*>(Q0l + dl) = ql.u;
    *reinterpret_cast<uint2*>(K0l + dl) = kl.u;
  }
}

// ----------------- head-0 scores + fused segment column sums ---------------
__global__ __launch_bounds__(256) void k_s0(
    const u16* Qh, const u16* Q0l, const u16* Kh, const u16* K0l,
    float* __restrict__ S0, float* __restrict__ seg)
{
  const int b = blockIdx.z;
  const int bm = blockIdx.y;  // j (query-row) tile == segment index
  const int bn = blockIdx.x;  // m (key-col) tile
  const int tid = threadIdx.x;
  if (bn > bm){               // above diagonal: S never read there; seg = 0
    if (tid < 128) seg[((size_t)b*NSEG + bm)*SEQ + bn*128 + tid] = 0.f;
    return;
  }
  float* Sb = S0 + (size_t)b*SEQ*SEQ;
  __shared__ __align__(16) u16 As[128*32];
  __shared__ __align__(16) u16 Bs[128*32];
  __shared__ float cs[2][128];
  const int wv = tid>>6, ln = tid&63;
  const int lane15 = ln&15, quad = ln>>4;
  const int wm = wv&1, wn = wv>>1;
  f32x4 acc[4][4];
  f32x4 z = {0.f,0.f,0.f,0.f};
#pragma unroll
  for (int i=0;i<4;++i)
#pragma unroll
    for (int j=0;j<4;++j) acc[i][j] = z;
  const u16* Qb  = Qh  + (size_t)b*N_HEADS*SEQ*D_HEAD;   // head 0
  const u16* Kb  = Kh  + (size_t)b*N_HEADS*SEQ*D_HEAD;
  const u16* Qlb = Q0l + (size_t)b*SEQ*D_HEAD;
  const u16* Klb = K0l + (size_t)b*SEQ*D_HEAD;
  const u16* Aps[3] = {Qb, Qb, Qlb};
  const u16* Bps[3] = {Kb, Klb, Kb};
  const int sRow = ln>>2, sCol = (ln&3)*8;
  const size_t rowBase = (size_t)bm*128, colBase = (size_t)bn*128;
  for (int p = 0; p < 3; ++p) {
    const u16* Ap = Aps[p];
    const u16* Bp = Bps[p];
    for (int kt = 0; kt < 2; ++kt) {
      __syncthreads();
#pragma unroll
      for (int c = 0; c < 2; ++c) {
        int chunk = wv*2 + c;
        int r = chunk*16 + sRow;
        const u16* ga = Ap + (rowBase + r)*D_HEAD + kt*32 + sCol;
        const u16* gb = Bp + (colBase + r)*D_HEAD + kt*32 + sCol;
        __builtin_amdgcn_global_load_lds(
            (const __attribute__((address_space(1))) void*)ga,
            (__attribute__((address_space(3))) void*)(As + chunk*512), 16, 0, 0);
        __builtin_amdgcn_global_load_lds(
            (const __attribute__((address_space(1))) void*)gb,
            (__attribute__((address_space(3))) void*)(Bs + chunk*512), 16, 0, 0);
      }
      __syncthreads();
      bf16x8 af[4], bfb[4];
#pragma unroll
      for (int t=0;t<4;++t){
        af[t]  = *reinterpret_cast<const bf16x8*>(As + (wm*64 + t*16 + lane15)*32 + quad*8);
        bfb[t] = *reinterpret_cast<const bf16x8*>(Bs + (wn*64 + t*16 + lane15)*32 + quad*8);
      }
#pragma unroll
      for (int i=0;i<4;++i)
#pragma unroll
        for (int j=0;j<4;++j)
          acc[i][j] = __builtin_amdgcn_mfma_f32_16x16x32_bf16(af[i], bfb[j], acc[i][j], 0,0,0);
    }
  }
  float csum[4] = {0.f,0.f,0.f,0.f};
#pragma unroll
  for (int i=0;i<4;++i){
#pragma unroll
    for (int j=0;j<4;++j){
#pragma unroll
      for (int r=0;r<4;++r){
        int jg = (int)rowBase + wm*64 + i*16 + quad*4 + r;
        int mg = (int)colBase + wn*64 + j*16 + lane15;
        float l = acc[i][j][r]*0.125f;
        float s = (mg >= 1 && mg < jg) ? fmaxf(l, 0.f) : 0.f;
        Sb[(size_t)jg*SEQ + mg] = s;
        csum[j] += s;
      }
    }
  }
#pragma unroll
  for (int j=0;j<4;++j){
    float v = csum[j];
    v += __shfl_xor(v, 16);
    v += __shfl_xor(v, 32);
    if (ln < 16) cs[wm][wn*64 + j*16 + ln] = v;
  }
  __syncthreads();
  if (tid < 128)
    seg[((size_t)b*NSEG + bm)*SEQ + bn*128 + tid] = cs[0][tid] + cs[1][tid];
}

// --- in place: S -> -F*log2e; prefix computed directly from seg sums -------
__global__ void k_seg_apply(float* __restrict__ SF, const float* __restrict__ seg){
  int m = blockIdx.x*256 + threadIdx.x;
  int s = blockIdx.y, b = blockIdx.z;
  const float* sb = seg + (size_t)b*NSEG*SEQ;
  float run = 0.f;
  for (int t=0; t<s; ++t) run += sb[(size_t)t*SEQ + m];
  float* Sb = SF + (size_t)b*SEQ*SEQ;
  const int j0 = s*SEGLEN;
  for (int i=0;i<SEGLEN;++i){
    size_t idx = (size_t)(j0 + i)*SEQ + m;
    float t = Sb[idx];
    Sb[idx] = -run*LOG2E;
    run += (j0 + i > m) ? t : 0.f;
  }
}

// ----- flash attention: 128-row Q tiles, fixed-max, double-buffered --------
// grid (16,16,2)=512 = exactly 2 blocks/CU; bound (256,2) -> 256-VGPR cap.
__global__ __launch_bounds__(256, 2) void k_attn(
    const u16* __restrict__ Qh, const u16* __restrict__ Kh,
    const u16* __restrict__ Vt, const float* __restrict__ F,
    u16* __restrict__ Ob)
{
  __shared__ __align__(16) u16 Ks[2][64*64];
  __shared__ __align__(16) u16 Vs[2][64*64];
  const int h = blockIdx.x, b = blockIdx.z;
  const int nt = b ? (int)(gridDim.y - 1 - blockIdx.y) : (int)blockIdx.y;
  const int tid = threadIdx.x, wv = tid>>6, ln = tid&63;
  const int lane15 = ln&15, quad = ln>>4;
  const u16* Qbh = Qh + ((size_t)(b*N_HEADS + h))*SEQ*D_HEAD;
  const u16* Kbh = Kh + ((size_t)(b*N_HEADS + h))*SEQ*D_HEAD;
  const u16* Vbh = Vt + ((size_t)(b*N_HEADS + h))*D_HEAD*SEQ;
  const float* Fb = F + (size_t)b*SEQ*SEQ;
  const int n0 = nt*128;
  const int swz = (ln&7) ^ ((ln>>3)&7);
  const int fswz = lane15 & 7;
  const int srow = ln>>3;
  const int nchunks = 2*nt + 2;

  bf16x8 qf[2][2];          // [ns][kt]
#pragma unroll
  for (int ns=0; ns<2; ++ns)
#pragma unroll
    for (int kt=0; kt<2; ++kt){
      int n = n0 + wv*32 + ns*16 + lane15;
      qf[ns][kt] = *reinterpret_cast<const bf16x8*>(Qbh + (size_t)n*D_HEAD + kt*32 + quad*8);
    }

  f32x4 z = {0.f,0.f,0.f,0.f};
  float psum[2] = {0.f, 0.f};
  f32x4 acc_o[2][4];
#pragma unroll
  for (int ns=0;ns<2;++ns)
#pragma unroll
    for (int no=0;no<4;++no) acc_o[ns][no] = z;

  auto stage = [&](int mc, int buf){
#pragma unroll
    for (int c=0;c<2;++c){
      int chunk = wv*2 + c;
      int r = chunk*8 + srow;
      const u16* gk = Kbh + (size_t)(mc*64 + r)*D_HEAD + swz*8;
      const u16* gv = Vbh + (size_t)r*SEQ + mc*64 + swz*8;
      __builtin_amdgcn_global_load_lds(
          (const __attribute__((address_space(1))) void*)gk,
          (__attribute__((address_space(3))) void*)(&Ks[buf][chunk*512]), 16, 0, 0);
      __builtin_amdgcn_global_load_lds(
          (const __attribute__((address_space(1))) void*)gv,
          (__attribute__((address_space(3))) void*)(&Vs[buf][chunk*512]), 16, 0, 0);
    }
  };
  stage(0, 0);
  const float c1 = 0.125f*LOG2E;

  for (int mc = 0; mc < nchunks; ++mc) {
    const int cur = mc & 1;
    __syncthreads();                       // drain: buf[cur] ready
    if (mc+1 < nchunks) stage(mc+1, 1-cur);
    const bool diag = (mc >= 2*nt);        // chunk may touch the diagonal
#pragma unroll
    for (int ns=0; ns<2; ++ns){
      const int n_loc = wv*32 + ns*16 + lane15;
      const int n_g = n0 + n_loc;
      const float* Fr = Fb + (size_t)n_g*SEQ + mc*64;
      // S^T: rows m (4 x 16), col n = lane15
      f32x4 accs[4];
#pragma unroll
      for (int ms=0;ms<4;++ms) accs[ms] = z;
#pragma unroll
      for (int kt=0; kt<2; ++kt){
#pragma unroll
        for (int ms=0; ms<4; ++ms){
          bf16x8 a = *reinterpret_cast<const bf16x8*>(
              &Ks[cur][(ms*16 + lane15)*64 + (((kt*4 + quad) ^ fswz) * 8)]);
          accs[ms] = __builtin_amdgcn_mfma_f32_16x16x32_bf16(a, qf[ns][kt], accs[ms], 0,0,0);
        }
      }
      // fixed-max softmax: p = exp2(score*log2e - F*log2e)
      uint32_t pw[4][2];
#pragma unroll
      for (int ms=0; ms<4; ++ms){
        f32x4 fv = *reinterpret_cast<const f32x4*>(Fr + ms*16 + quad*4);
        f32x4 t = accs[ms];
        float p[4];
#pragma unroll
        for (int r=0;r<4;++r){
          float l2 = fmaf(t[r], c1, fv[r]);
          if (diag){
            int m_g = mc*64 + ms*16 + quad*4 + r;
            l2 = (m_g > n_g) ? -1e30f : l2;
          }
          p[r] = __builtin_amdgcn_exp2f(l2);
        }
        psum[ns] += (p[0]+p[1]) + (p[2]+p[3]);
        pw[ms][0] = pack2(p[0], p[1]);
        pw[ms][1] = pack2(p[2], p[3]);
      }
      // P relayout: C-layout (m=quad*4+r) -> A-fragment (k=quad*8+j)
#pragma unroll
      for (int kt=0; kt<2; ++kt){
        union { uint32_t u[4]; bf16x8 v; } pa;
#pragma unroll
        for (int w=0; w<4; ++w){
          int sl = lane15 + 16*((quad&1)*2 + (w>>1));
          uint32_t t0 = (uint32_t)__shfl((int)pw[2*kt  ][w&1], sl);
          uint32_t t1 = (uint32_t)__shfl((int)pw[2*kt+1][w&1], sl);
          pa.u[w] = (quad < 2) ? t0 : t1;
        }
#pragma unroll
        for (int no=0; no<4; ++no){
          int d = no*16 + lane15;
          bf16x8 vb = *reinterpret_cast<const bf16x8*>(
              &Vs[cur][d*64 + (((kt*4 + quad) ^ (d&7)) * 8)]);
          acc_o[ns][no] = __builtin_amdgcn_mfma_f32_16x16x32_bf16(pa.v, vb, acc_o[ns][no], 0,0,0);
        }
      }
    }
  }
#pragma unroll
  for (int ns=0; ns<2; ++ns){
    float s = psum[ns];
    s += __shfl_xor(s, 16);
    s += __shfl_xor(s, 32);
    f32x4 inv;
#pragma unroll
    for (int r=0;r<4;++r)
      inv[r] = __builtin_amdgcn_rcpf(__shfl(s, quad*4 + r));
#pragma unroll
    for (int no=0; no<4; ++no){
#pragma unroll
      for (int r=0;r<4;++r){
        float o = acc_o[ns][no][r] * inv[r];
        int row = n0 + wv*32 + ns*16 + quad*4 + r;
        Ob[((size_t)(b*SEQ + row))*D_MODEL + h*64 + no*16 + lane15] = f2bf(o);
      }
    }
  }
}

// ------------------------ NT GEMM, 128x64 tile (O-proj) --------------------
__global__ __launch_bounds__(256) void k_gemm_nt64(
    const u16* __restrict__ A0, const u16* __restrict__ B0,
    float* __restrict__ C, int N, int K)
{
  __shared__ __align__(16) u16 As[128*32];
  __shared__ __align__(16) u16 Bs[64*32];
  const int tid = threadIdx.x, wv = tid>>6, ln = tid&63;
  const int lane15 = ln&15, quad = ln>>4;
  const int wm = wv&1, wn = wv>>1;
  const size_t rowBase = (size_t)blockIdx.y*128, colBase = (size_t)blockIdx.x*64;
  f32x4 acc[4][2];
  f32x4 z = {0.f,0.f,0.f,0.f};
#pragma unroll
  for (int i=0;i<4;++i){ acc[i][0] = z; acc[i][1] = z; }
  const int ktiles = K >> 5;
  const int sRow = ln>>2, sCol = (ln&3)*8;
  for (int kt = 0; kt < ktiles; ++kt) {
    __syncthreads();
#pragma unroll
    for (int c = 0; c < 2; ++c) {
      int chunk = wv*2 + c;
      int r = chunk*16 + sRow;
      const u16* ga = A0 + (rowBase + r)*K + kt*32 + sCol;
      __builtin_amdgcn_global_load_lds(
          (const __attribute__((address_space(1))) void*)ga,
          (__attribute__((address_space(3))) void*)(As + chunk*512), 16, 0, 0);
    }
    {
      int r = wv*16 + sRow;
      const u16* gb = B0 + (colBase + r)*K + kt*32 + sCol;
      __builtin_amdgcn_global_load_lds(
          (const __attribute__((address_space(1))) void*)gb,
          (__attribute__((address_space(3))) void*)(Bs + wv*512), 16, 0, 0);
    }
    __syncthreads();
    bf16x8 af[4], bfb[2];
#pragma unroll
    for (int t=0;t<4;++t)
      af[t]  = *reinterpret_cast<const bf16x8*>(As + (wm*64 + t*16 + lane15)*32 + quad*8);
#pragma unroll
    for (int t=0;t<2;++t)
      bfb[t] = *reinterpret_cast<const bf16x8*>(Bs + (wn*32 + t*16 + lane15)*32 + quad*8);
#pragma unroll
    for (int i=0;i<4;++i)
#pragma unroll
      for (int j=0;j<2;++j)
        acc[i][j] = __builtin_amdgcn_mfma_f32_16x16x32_bf16(af[i], bfb[j], acc[i][j], 0,0,0);
  }
#pragma unroll
  for (int i=0;i<4;++i){
    size_t row = rowBase + wm*64 + i*16 + quad*4;
#pragma unroll
    for (int j=0;j<2;++j){
      size_t col = colBase + wn*32 + j*16 + lane15;
#pragma unroll
      for (int r=0;r<4;++r)
        C[(row+r)*N + col] = acc[i][j][r];
    }
  }
}

// ------------------------------- launcher ----------------------------------
extern "C" void kernel_launch(void* const* d_in, const int* in_sizes, int n_in,
                              void* d_out, int out_size, void* d_ws, size_t ws_size,
                              hipStream_t stream)
{
  (void)in_sizes; (void)n_in; (void)out_size; (void)ws_size;
  const float* X  = (const float*)d_in[0];
  const float* Wq = (const float*)d_in[1];
  const float* Wk = (const float*)d_in[2];
  const float* Wv = (const float*)d_in[3];
  const float* Wo = (const float*)d_in[4];
  const float* gq = (const float*)d_in[5];
  const float* bq = (const float*)d_in[6];
  const float* gk = (const float*)d_in[7];
  const float* bk = (const float*)d_in[8];
  float* out = (float*)d_out;

  char* ws = (char*)d_ws;
  size_t off = 0;
  auto alloc = [&](size_t bytes)->char*{
    char* p = ws + off; off += (bytes + 255) & ~(size_t)255; return p;
  };
  u16* Xhi  = (u16*)alloc((size_t)ROWS*D_MODEL*2);
  u16* Xlo  = (u16*)alloc((size_t)ROWS*D_MODEL*2);
  u16* Wqkh = (u16*)alloc((size_t)2*D_MODEL*D_MODEL*2);  // [Wq;Wk] hi
  u16* Wqkl = (u16*)alloc((size_t)2*D_MODEL*D_MODEL*2);  // [Wq;Wk] lo
  u16* Wvb  = (u16*)alloc((size_t)D_MODEL*D_MODEL*2);
  u16* Wob  = (u16*)alloc((size_t)D_MODEL*D_MODEL*2);
  u16* Qhp  = (u16*)alloc((size_t)BATCH*N_HEADS*SEQ*D_HEAD*2);
  u16* Khp  = (u16*)alloc((size_t)BATCH*N_HEADS*SEQ*D_HEAD*2);
  u16* Q0l  = (u16*)alloc((size_t)BATCH*SEQ*D_HEAD*2);
  u16* K0l  = (u16*)alloc((size_t)BATCH*SEQ*D_HEAD*2);
  u16* Vtp  = (u16*)alloc((size_t)BATCH*N_HEADS*D_HEAD*SEQ*2);
  u16* Obf  = (u16*)alloc((size_t)ROWS*D_MODEL*2);
  float* Dlt = (float*)alloc((size_t)ROWS*128*4);        // head-0 corrections
  float* Seg = (float*)alloc((size_t)BATCH*NSEG*SEQ*4);
  float* SF  = (float*)alloc((size_t)BATCH*SEQ*SEQ*4);   // 33.5 MB
  float* C32 = SF;    // QK-proj fp32 scratch aliases SF (consumed before s0)

  // Dlt must start at zero (harness poisons ws with 0xAA)
  hipMemsetAsync(Dlt, 0, (size_t)ROWS*128*4, stream);

  // all casts, one launch
  k_cast_all<<<8192, 256, 0, stream>>>(
      X, Xhi, Xlo,
      Wq, Wqkh, Wqkl,
      Wk, Wqkh + (size_t)D_MODEL*D_MODEL, Wqkl + (size_t)D_MODEL*D_MODEL,
      Wv, Wvb, Wo, Wob);

  // qk GEMM + head-0 corr (Dlt) + V^T GEMM, one launch
  k_mega<<<1152, 256, 0, stream>>>(Xhi, Xlo, Wqkh, Wqkl, Wvb, C32, Dlt, Vtp);

  // both LNs + packs (head-0 corrected via Dlt)
  k_ln_pack2<<<ROWS, 256, 0, stream>>>(C32, Dlt, gq, bq, gk, bk, Qhp, Khp, Q0l, K0l);
  // head-0 scores + fused segment sums; apply (prefix from seg; -F*log2e)
  k_s0<<<dim3(16, 16, BATCH), 256, 0, stream>>>(Qhp, Q0l, Khp, K0l, SF, Seg);
  k_seg_apply<<<dim3(8, NSEG, BATCH), 256, 0, stream>>>(SF, Seg);
  // attention (128-row Q tiles, 2 blocks/CU)
  k_attn<<<dim3(N_HEADS, SEQ/128, BATCH), 256, 0, stream>>>(Qhp, Khp, Vtp, SF, Obf);
  // output projection
  k_gemm_nt64<<<dim3(16, 32), 256, 0, stream>>>(Obf, Wob, out, D_MODEL, D_MODEL);
}

// Round 7
// 311.881 us; speedup vs baseline: 1.0712x; 1.0712x over previous
//
#include <hip/hip_runtime.h>
#include <cstdint>
#include <cstddef>

// ---------------------------------------------------------------------------
// MultiheadSelectiveAttention (B=2, S=2048, D=1024, H=16, dh=64), fp32 in/out.
//   k_cast_all: X,Wq,Wk -> hi/lo bf16; Wv,Wo -> bf16 (one launch)
//   k_mega: qk GEMM (512 blk) + head0 corr->Dlt (128 blk) + V^T GEMM (512 blk)
//   k_ln_pack2: LN(Q),LN(K); head-0 cols += Dlt -> bf16 packs (+head0 lo)
//   k_s0: head-0 scores (3-pass split) + fused 32-row segment column sums
//   k_seg_apply: in-place S -> -F*log2e, 32-row segments (4 blk/CU, short
//                serial chain; prefix from <=63 independent seg reads)
//   k_attn: 64-row Q tiles (4 blk/CU — proven best), fixed-max softmax,
//           dbuf DMA staging, register P via quad shuffles
//   k_gemm_nt64: out = Obf @ Wo^T
// ---------------------------------------------------------------------------

typedef unsigned short u16;
typedef __attribute__((ext_vector_type(8))) __bf16 bf16x8;
typedef __attribute__((ext_vector_type(4))) float f32x4;

#define D_MODEL 1024
#define N_HEADS 16
#define BATCH   2
#define SEQ     2048
#define D_HEAD  64
#define ROWS    (BATCH*SEQ)   /* 4096 */
#define NSEG    64
#define SEGLEN  32
#define LOG2E   1.44269504f

static __device__ __forceinline__ u16 f2bf(float f){
  union { float f; uint32_t u; } v; v.f = f;
  uint32_t r = v.u + 0x7fffu + ((v.u >> 16) & 1u);
  return (u16)(r >> 16);
}
static __device__ __forceinline__ float bf2f(u16 h){
  union { uint32_t u; float f; } v; v.u = ((uint32_t)h) << 16;
  return v.f;
}
// round-half-up bf16 pair pack (cheap: 2 adds + merge)
static __device__ __forceinline__ uint32_t pack2(float a, float b){
  uint32_t ua = __float_as_uint(a) + 0x8000u;
  uint32_t ub = __float_as_uint(b) + 0x8000u;
  return (ua >> 16) | (ub & 0xffff0000u);
}

// ------------------------- merged cast kernel ------------------------------
__global__ void k_cast_all(const float* __restrict__ X,
                           u16* __restrict__ Xhi, u16* __restrict__ Xlo,
                           const float* __restrict__ Wq,
                           u16* __restrict__ Wqh, u16* __restrict__ Wql,
                           const float* __restrict__ Wk,
                           u16* __restrict__ Wkh, u16* __restrict__ Wkl,
                           const float* __restrict__ Wv, u16* __restrict__ Wvb,
                           const float* __restrict__ Wo, u16* __restrict__ Wob){
  int i = blockIdx.x*256 + threadIdx.x;   // float4 index
  if (i < 1572864){                       // split: X | Wq | Wk
    const float* src; u16 *dh, *dl; int base;
    if (i < 1048576){ src = X;  dh = Xhi; dl = Xlo; base = i; }
    else if (i < 1310720){ src = Wq; dh = Wqh; dl = Wql; base = i - 1048576; }
    else { src = Wk; dh = Wkh; dl = Wkl; base = i - 1310720; }
    float4 v = reinterpret_cast<const float4*>(src)[base];
    float vs[4] = {v.x, v.y, v.z, v.w};
    union { u16 s[4]; uint2 u; } uh, ul;
#pragma unroll
    for (int r=0;r<4;++r){
      uh.s[r] = f2bf(vs[r]);
      ul.s[r] = f2bf(vs[r] - bf2f(uh.s[r]));
    }
    reinterpret_cast<uint2*>(dh)[base] = uh.u;
    reinterpret_cast<uint2*>(dl)[base] = ul.u;
  } else {                                // plain: Wv | Wo
    const float* src; u16* dst; int base;
    if (i < 1835008){ src = Wv; dst = Wvb; base = i - 1572864; }
    else { src = Wo; dst = Wob; base = i - 1835008; }
    float4 v = reinterpret_cast<const float4*>(src)[base];
    float vs[4] = {v.x, v.y, v.z, v.w};
    union { u16 s[4]; uint2 u; } uh;
#pragma unroll
    for (int r=0;r<4;++r) uh.s[r] = f2bf(vs[r]);
    reinterpret_cast<uint2*>(dst)[base] = uh.u;
  }
}

// ---- mega kernel: qk (0-511) | corr->Dlt (512-639) | vt (640-1151) --------
__global__ __launch_bounds__(256) void k_mega(
    const u16* __restrict__ Xhi, const u16* __restrict__ Xlo,
    const u16* __restrict__ Wh,  const u16* __restrict__ Wl,
    const u16* __restrict__ Wvb,
    float* __restrict__ C, float* __restrict__ Dlt, u16* __restrict__ Vt)
{
  __shared__ __align__(16) u16 smem[64*136];   // 17408 B, shared by all roles
  const int bid = blockIdx.x;
  const int tid = threadIdx.x, wv = tid>>6, ln = tid&63;
  const int lane15 = ln&15, quad = ln>>4;
  const int wm = wv&1, wn = wv>>1;
  const int sRow = ln>>2, sCol = (ln&3)*8;
  f32x4 z = {0.f,0.f,0.f,0.f};

  if (bid < 512){
    // ---------------- QK projection: 128x128 tile, 1-pass ------------------
    u16* As = smem;            // 128*32
    u16* Bs = smem + 4096;     // 128*32
    const size_t rowBase = (size_t)(bid>>4)*128, colBase = (size_t)(bid&15)*128;
    f32x4 acc[4][4];
#pragma unroll
    for (int i=0;i<4;++i)
#pragma unroll
      for (int j=0;j<4;++j) acc[i][j] = z;
    for (int kt = 0; kt < 32; ++kt) {
      __syncthreads();
#pragma unroll
      for (int c = 0; c < 2; ++c) {
        int chunk = wv*2 + c;
        int r = chunk*16 + sRow;
        const u16* ga = Xhi + (rowBase + r)*1024 + kt*32 + sCol;
        const u16* gb = Wh  + (colBase + r)*1024 + kt*32 + sCol;
        __builtin_amdgcn_global_load_lds(
            (const __attribute__((address_space(1))) void*)ga,
            (__attribute__((address_space(3))) void*)(As + chunk*512), 16, 0, 0);
        __builtin_amdgcn_global_load_lds(
            (const __attribute__((address_space(1))) void*)gb,
            (__attribute__((address_space(3))) void*)(Bs + chunk*512), 16, 0, 0);
      }
      __syncthreads();
      bf16x8 af[4], bfb[4];
#pragma unroll
      for (int t=0;t<4;++t){
        af[t]  = *reinterpret_cast<const bf16x8*>(As + (wm*64 + t*16 + lane15)*32 + quad*8);
        bfb[t] = *reinterpret_cast<const bf16x8*>(Bs + (wn*64 + t*16 + lane15)*32 + quad*8);
      }
#pragma unroll
      for (int i=0;i<4;++i)
#pragma unroll
        for (int j=0;j<4;++j)
          acc[i][j] = __builtin_amdgcn_mfma_f32_16x16x32_bf16(af[i], bfb[j], acc[i][j], 0,0,0);
    }
#pragma unroll
    for (int i=0;i<4;++i){
      size_t row = rowBase + wm*64 + i*16 + quad*4;
#pragma unroll
      for (int j=0;j<4;++j){
        size_t col = colBase + wn*64 + j*16 + lane15;
#pragma unroll
        for (int r=0;r<4;++r)
          C[(row+r)*2048 + col] = acc[i][j][r];
      }
    }
  } else if (bid < 640){
    // ---- head-0 correction: Dlt = Xhi@Wlo^T + Xlo@Whi^T (per pass) --------
    u16* As = smem;            // 128*32
    u16* Bs = smem + 4096;     // 64*32
    const int idx = bid - 512;          // 0..127
    const int cx = idx & 1;             // Q / K col-group
    const int cy = (idx >> 1) & 31;     // row tile
    const int cz = idx >> 6;            // pass
    const size_t rowBase = (size_t)cy*128;
    const size_t wbase = cx ? (size_t)1024*1024 : 0;
    const u16* Ap = cz ? Xlo : Xhi;
    const u16* Bp = (cz ? Wh : Wl) + wbase;
    f32x4 acc[4][2];
#pragma unroll
    for (int i=0;i<4;++i){ acc[i][0] = z; acc[i][1] = z; }
    for (int kt = 0; kt < 32; ++kt) {
      __syncthreads();
#pragma unroll
      for (int c = 0; c < 2; ++c) {
        int chunk = wv*2 + c;
        int r = chunk*16 + sRow;
        const u16* ga = Ap + (rowBase + r)*1024 + kt*32 + sCol;
        __builtin_amdgcn_global_load_lds(
            (const __attribute__((address_space(1))) void*)ga,
            (__attribute__((address_space(3))) void*)(As + chunk*512), 16, 0, 0);
      }
      {
        int r = wv*16 + sRow;
        const u16* gb = Bp + (size_t)r*1024 + kt*32 + sCol;
        __builtin_amdgcn_global_load_lds(
            (const __attribute__((address_space(1))) void*)gb,
            (__attribute__((address_space(3))) void*)(Bs + wv*512), 16, 0, 0);
      }
      __syncthreads();
      bf16x8 af[4], bfb[2];
#pragma unroll
      for (int t=0;t<4;++t)
        af[t]  = *reinterpret_cast<const bf16x8*>(As + (wm*64 + t*16 + lane15)*32 + quad*8);
#pragma unroll
      for (int t=0;t<2;++t)
        bfb[t] = *reinterpret_cast<const bf16x8*>(Bs + (wn*32 + t*16 + lane15)*32 + quad*8);
#pragma unroll
      for (int i=0;i<4;++i)
#pragma unroll
        for (int j=0;j<2;++j)
          acc[i][j] = __builtin_amdgcn_mfma_f32_16x16x32_bf16(af[i], bfb[j], acc[i][j], 0,0,0);
    }
#pragma unroll
    for (int i=0;i<4;++i){
      size_t row = rowBase + wm*64 + i*16 + quad*4;
#pragma unroll
      for (int j=0;j<2;++j){
        size_t col = (size_t)cx*64 + wn*32 + j*16 + lane15;
#pragma unroll
        for (int r=0;r<4;++r)
          atomicAdd(&Dlt[(row+r)*128 + col], acc[i][j][r]);
      }
    }
  } else {
    // ------- V projection with fused V^T bf16 epilogue (LDS transpose) -----
    u16* As = smem;            // 128*32
    u16* Bs = smem + 4096;     // 64*32
    const int idx = bid - 640;          // 0..511
    const int bx = idx & 15, by = idx >> 4;
    const size_t rowBase = (size_t)by*128, colBase = (size_t)bx*64;
    f32x4 acc[4][2];
#pragma unroll
    for (int i=0;i<4;++i){ acc[i][0] = z; acc[i][1] = z; }
    for (int kt = 0; kt < 32; ++kt) {
      __syncthreads();
#pragma unroll
      for (int c = 0; c < 2; ++c) {
        int chunk = wv*2 + c;
        int r = chunk*16 + sRow;
        const u16* ga = Xhi + (rowBase + r)*1024 + kt*32 + sCol;
        __builtin_amdgcn_global_load_lds(
            (const __attribute__((address_space(1))) void*)ga,
            (__attribute__((address_space(3))) void*)(As + chunk*512), 16, 0, 0);
      }
      {
        int r = wv*16 + sRow;
        const u16* gb = Wvb + (colBase + r)*1024 + kt*32 + sCol;
        __builtin_amdgcn_global_load_lds(
            (const __attribute__((address_space(1))) void*)gb,
            (__attribute__((address_space(3))) void*)(Bs + wv*512), 16, 0, 0);
      }
      __syncthreads();
      bf16x8 af[4], bfb[2];
#pragma unroll
      for (int t=0;t<4;++t)
        af[t]  = *reinterpret_cast<const bf16x8*>(As + (wm*64 + t*16 + lane15)*32 + quad*8);
#pragma unroll
      for (int t=0;t<2;++t)
        bfb[t] = *reinterpret_cast<const bf16x8*>(Bs + (wn*32 + t*16 + lane15)*32 + quad*8);
#pragma unroll
      for (int i=0;i<4;++i)
#pragma unroll
        for (int j=0;j<2;++j)
          acc[i][j] = __builtin_amdgcn_mfma_f32_16x16x32_bf16(af[i], bfb[j], acc[i][j], 0,0,0);
    }
    // transpose epilogue: stage bf16 tile as [d 64][n 128] (stride 136)
    __syncthreads();
#pragma unroll
    for (int i=0;i<4;++i){
      int nl = wm*64 + i*16 + quad*4;
#pragma unroll
      for (int j=0;j<2;++j){
        int dl = wn*32 + j*16 + lane15;
#pragma unroll
        for (int r=0;r<4;++r)
          smem[dl*136 + nl + r] = f2bf(acc[i][j][r]);
      }
    }
    __syncthreads();
    const int b = by >> 4;
    const int n0 = (by & 15) * 128;
    const int bh = b*N_HEADS + bx;
    const int d = tid >> 2, seg = tid & 3;
    u16* dst = Vt + ((size_t)(bh*64 + d))*SEQ + n0 + seg*32;
    const u16* srcl = smem + d*136 + seg*32;
#pragma unroll
    for (int k=0;k<4;++k)
      *reinterpret_cast<uint4*>(dst + k*8) = *reinterpret_cast<const uint4*>(srcl + k*8);
  }
}

// --------- merged LN for Q and K + bf16 head packs (+ head0 corr) ----------
__global__ __launch_bounds__(256) void k_ln_pack2(
    const float* __restrict__ C, const float* __restrict__ Dlt,
    const float* __restrict__ gq, const float* __restrict__ bq,
    const float* __restrict__ gk, const float* __restrict__ bk,
    u16* __restrict__ Qh, u16* __restrict__ Kh,
    u16* __restrict__ Q0l, u16* __restrict__ K0l)
{
  const int row = blockIdx.x;
  const int tid = threadIdx.x;
  const float* cr = C + (size_t)row*2048;
  float4 vq = reinterpret_cast<const float4*>(cr)[tid];
  float4 vk = reinterpret_cast<const float4*>(cr)[256 + tid];
  // head-0 columns get the split-precision correction BEFORE stats
  const int h = tid >> 4;
  if (h == 0){
    float4 dq = reinterpret_cast<const float4*>(Dlt + (size_t)row*128)[tid&15];
    vq.x+=dq.x; vq.y+=dq.y; vq.z+=dq.z; vq.w+=dq.w;
    float4 dk = reinterpret_cast<const float4*>(Dlt + (size_t)row*128 + 64)[tid&15];
    vk.x+=dk.x; vk.y+=dk.y; vk.z+=dk.z; vk.w+=dk.w;
  }
  float sq  = vq.x+vq.y+vq.z+vq.w;
  float s2q = vq.x*vq.x+vq.y*vq.y+vq.z*vq.z+vq.w*vq.w;
  float sk  = vk.x+vk.y+vk.z+vk.w;
  float s2k = vk.x*vk.x+vk.y*vk.y+vk.z*vk.z+vk.w*vk.w;
#pragma unroll
  for (int o=32;o;o>>=1){
    sq += __shfl_xor(sq,o);  s2q += __shfl_xor(s2q,o);
    sk += __shfl_xor(sk,o);  s2k += __shfl_xor(s2k,o);
  }
  __shared__ float red[4][4];
  if ((tid&63)==0){
    red[tid>>6][0]=sq; red[tid>>6][1]=s2q; red[tid>>6][2]=sk; red[tid>>6][3]=s2k;
  }
  __syncthreads();
  sq  = red[0][0]+red[1][0]+red[2][0]+red[3][0];
  s2q = red[0][1]+red[1][1]+red[2][1]+red[3][1];
  sk  = red[0][2]+red[1][2]+red[2][2]+red[3][2];
  s2k = red[0][3]+red[1][3]+red[2][3]+red[3][3];
  const float muq = sq*(1.f/D_MODEL);
  const float rsq = rsqrtf(s2q*(1.f/D_MODEL) - muq*muq + 1e-5f);
  const float muk = sk*(1.f/D_MODEL);
  const float rsk = rsqrtf(s2k*(1.f/D_MODEL) - muk*muk + 1e-5f);
  const int b = row >> 11, n = row & (SEQ-1);
  const int d0 = (tid & 15)*4;
  float4 gqv = reinterpret_cast<const float4*>(gq)[tid];
  float4 bqv = reinterpret_cast<const float4*>(bq)[tid];
  float4 gkv = reinterpret_cast<const float4*>(gk)[tid];
  float4 bkv = reinterpret_cast<const float4*>(bk)[tid];
  float xq[4] = {vq.x,vq.y,vq.z,vq.w}, xk[4] = {vk.x,vk.y,vk.z,vk.w};
  float gQ[4] = {gqv.x,gqv.y,gqv.z,gqv.w}, bQ[4] = {bqv.x,bqv.y,bqv.z,bqv.w};
  float gK[4] = {gkv.x,gkv.y,gkv.z,gkv.w}, bK[4] = {bkv.x,bkv.y,bkv.z,bkv.w};
  union { u16 s[4]; uint2 u; } qh, ql, kh, kl;
#pragma unroll
  for (int r=0;r<4;++r){
    float yq = (xq[r]-muq)*rsq*gQ[r] + bQ[r];
    qh.s[r] = f2bf(yq);
    ql.s[r] = f2bf(yq - bf2f(qh.s[r]));
    float yk = (xk[r]-muk)*rsk*gK[r] + bK[r];
    kh.s[r] = f2bf(yk);
    kl.s[r] = f2bf(yk - bf2f(kh.s[r]));
  }
  size_t dst = (((size_t)(b*N_HEADS + h))*SEQ + n)*D_HEAD + d0;
  *reinterpret_cast<uint2*>(Qh + dst) = qh.u;
  *reinterpret_cast<uint2*>(Kh + dst) = kh.u;
  if (h == 0){
    size_t dl = ((size_t)b*SEQ + n)*D_HEAD + d0;
    *reinterpret_cast<uint2*>(Q0l + dl) = ql.u;
    *reinterpret_cast<uint2*>(K0l + dl) = kl.u;
  }
}

// -------- head-0 scores + fused 32-row segment column sums -----------------
__global__ __launch_bounds__(256) void k_s0(
    const u16* Qh, const u16* Q0l, const u16* Kh, const u16* K0l,
    float* __restrict__ S0, float* __restrict__ seg)
{
  const int b = blockIdx.z;
  const int bm = blockIdx.y;  // j (query-row) 128-tile -> segments 4bm..4bm+3
  const int bn = blockIdx.x;  // m (key-col) tile
  const int tid = threadIdx.x;
  if (bn > bm){               // above diagonal: S never read there; seg = 0
    for (int t = tid; t < 512; t += 256)
      seg[((size_t)b*NSEG + bm*4 + (t>>7))*SEQ + bn*128 + (t&127)] = 0.f;
    return;
  }
  float* Sb = S0 + (size_t)b*SEQ*SEQ;
  __shared__ __align__(16) u16 As[128*32];
  __shared__ __align__(16) u16 Bs[128*32];
  __shared__ float cs[4][128];
  const int wv = tid>>6, ln = tid&63;
  const int lane15 = ln&15, quad = ln>>4;
  const int wm = wv&1, wn = wv>>1;
  f32x4 acc[4][4];
  f32x4 z = {0.f,0.f,0.f,0.f};
#pragma unroll
  for (int i=0;i<4;++i)
#pragma unroll
    for (int j=0;j<4;++j) acc[i][j] = z;
  const u16* Qb  = Qh  + (size_t)b*N_HEADS*SEQ*D_HEAD;   // head 0
  const u16* Kb  = Kh  + (size_t)b*N_HEADS*SEQ*D_HEAD;
  const u16* Qlb = Q0l + (size_t)b*SEQ*D_HEAD;
  const u16* Klb = K0l + (size_t)b*SEQ*D_HEAD;
  const u16* Aps[3] = {Qb, Qb, Qlb};
  const u16* Bps[3] = {Kb, Klb, Kb};
  const int sRow = ln>>2, sCol = (ln&3)*8;
  const size_t rowBase = (size_t)bm*128, colBase = (size_t)bn*128;
  for (int p = 0; p < 3; ++p) {
    const u16* Ap = Aps[p];
    const u16* Bp = Bps[p];
    for (int kt = 0; kt < 2; ++kt) {
      __syncthreads();
#pragma unroll
      for (int c = 0; c < 2; ++c) {
        int chunk = wv*2 + c;
        int r = chunk*16 + sRow;
        const u16* ga = Ap + (rowBase + r)*D_HEAD + kt*32 + sCol;
        const u16* gb = Bp + (colBase + r)*D_HEAD + kt*32 + sCol;
        __builtin_amdgcn_global_load_lds(
            (const __attribute__((address_space(1))) void*)ga,
            (__attribute__((address_space(3))) void*)(As + chunk*512), 16, 0, 0);
        __builtin_amdgcn_global_load_lds(
            (const __attribute__((address_space(1))) void*)gb,
            (__attribute__((address_space(3))) void*)(Bs + chunk*512), 16, 0, 0);
      }
      __syncthreads();
      bf16x8 af[4], bfb[4];
#pragma unroll
      for (int t=0;t<4;++t){
        af[t]  = *reinterpret_cast<const bf16x8*>(As + (wm*64 + t*16 + lane15)*32 + quad*8);
        bfb[t] = *reinterpret_cast<const bf16x8*>(Bs + (wn*64 + t*16 + lane15)*32 + quad*8);
      }
#pragma unroll
      for (int i=0;i<4;++i)
#pragma unroll
        for (int j=0;j<4;++j)
          acc[i][j] = __builtin_amdgcn_mfma_f32_16x16x32_bf16(af[i], bfb[j], acc[i][j], 0,0,0);
    }
  }
  float csum[2][4] = {{0.f,0.f,0.f,0.f},{0.f,0.f,0.f,0.f}};
#pragma unroll
  for (int i=0;i<4;++i){
#pragma unroll
    for (int j=0;j<4;++j){
#pragma unroll
      for (int r=0;r<4;++r){
        int jg = (int)rowBase + wm*64 + i*16 + quad*4 + r;
        int mg = (int)colBase + wn*64 + j*16 + lane15;
        float l = acc[i][j][r]*0.125f;
        float s = (mg >= 1 && mg < jg) ? fmaxf(l, 0.f) : 0.f;
        Sb[(size_t)jg*SEQ + mg] = s;
        csum[i>>1][j] += s;
      }
    }
  }
#pragma unroll
  for (int h2=0;h2<2;++h2){
#pragma unroll
    for (int j=0;j<4;++j){
      float v = csum[h2][j];
      v += __shfl_xor(v, 16);
      v += __shfl_xor(v, 32);
      if (ln < 16) cs[wm*2 + h2][wn*64 + j*16 + ln] = v;
    }
  }
  __syncthreads();
  for (int t = tid; t < 512; t += 256)
    seg[((size_t)b*NSEG + bm*4 + (t>>7))*SEQ + bn*128 + (t&127)] = cs[t>>7][t&127];
}

// --- in place: S -> -F*log2e; 32-row segments; prefix from seg sums --------
__global__ void k_seg_apply(float* __restrict__ SF, const float* __restrict__ seg){
  int m = blockIdx.x*256 + threadIdx.x;
  int s = blockIdx.y, b = blockIdx.z;
  const float* sb = seg + (size_t)b*NSEG*SEQ;
  float run = 0.f;
  for (int t=0; t<s; ++t) run += sb[(size_t)t*SEQ + m];   // independent loads
  float* Sb = SF + (size_t)b*SEQ*SEQ;
  const int j0 = s*SEGLEN;
#pragma unroll 8
  for (int i=0;i<SEGLEN;++i){
    size_t idx = (size_t)(j0 + i)*SEQ + m;
    float t = Sb[idx];
    Sb[idx] = -run*LOG2E;
    run += (j0 + i > m) ? t : 0.f;
  }
}

// ------------- flash attention, fixed-max softmax, double-buffered ---------
// 64-row Q tiles, grid 1024 = 4 blocks/CU (proven best in R3/R5).
__global__ __launch_bounds__(256, 4) void k_attn(
    const u16* __restrict__ Qh, const u16* __restrict__ Kh,
    const u16* __restrict__ Vt, const float* __restrict__ F,
    u16* __restrict__ Ob)
{
  __shared__ __align__(16) u16 Ks[2][64*64];
  __shared__ __align__(16) u16 Vs[2][64*64];
  const int h = blockIdx.x, b = blockIdx.z;
  const int nt = b ? (int)(gridDim.y - 1 - blockIdx.y) : (int)blockIdx.y;
  const int tid = threadIdx.x, wv = tid>>6, ln = tid&63;
  const int lane15 = ln&15, quad = ln>>4;
  const u16* Qbh = Qh + ((size_t)(b*N_HEADS + h))*SEQ*D_HEAD;
  const u16* Kbh = Kh + ((size_t)(b*N_HEADS + h))*SEQ*D_HEAD;
  const u16* Vbh = Vt + ((size_t)(b*N_HEADS + h))*D_HEAD*SEQ;
  const float* Fb = F + (size_t)b*SEQ*SEQ;
  const int n_loc = wv*16 + lane15;
  const int n_g = nt*64 + n_loc;
  const int swz = (ln&7) ^ ((ln>>3)&7);
  const int fswz = lane15 & 7;
  const int srow = ln>>3;

  bf16x8 qf[2];
#pragma unroll
  for (int kt=0; kt<2; ++kt)
    qf[kt] = *reinterpret_cast<const bf16x8*>(Qbh + (size_t)n_g*D_HEAD + kt*32 + quad*8);

  f32x4 z = {0.f,0.f,0.f,0.f};
  f32x4 psum = z;
  f32x4 acc_o[4];
#pragma unroll
  for (int no=0;no<4;++no) acc_o[no] = z;

  // stage K/V chunk mt into buffer buf
  auto stage = [&](int mt, int buf){
#pragma unroll
    for (int c=0;c<2;++c){
      int chunk = wv*2 + c;
      int r = chunk*8 + srow;
      const u16* gk = Kbh + (size_t)(mt*64 + r)*D_HEAD + swz*8;
      const u16* gv = Vbh + (size_t)r*SEQ + mt*64 + swz*8;
      __builtin_amdgcn_global_load_lds(
          (const __attribute__((address_space(1))) void*)gk,
          (__attribute__((address_space(3))) void*)(&Ks[buf][chunk*512]), 16, 0, 0);
      __builtin_amdgcn_global_load_lds(
          (const __attribute__((address_space(1))) void*)gv,
          (__attribute__((address_space(3))) void*)(&Vs[buf][chunk*512]), 16, 0, 0);
    }
  };
  stage(0, 0);
  const float c1 = 0.125f*LOG2E;

  for (int mt = 0; mt <= nt; ++mt) {
    const int cur = mt & 1;
    __syncthreads();                    // vmcnt(0) drain: buf[cur] ready
    if (mt < nt) stage(mt+1, 1-cur);    // prefetch next chunk (overlapped)
    // F prefetch for this chunk (already -F*log2e)
    const float* Fr = Fb + (size_t)n_g*SEQ + mt*64;
    f32x4 fv[4];
#pragma unroll
    for (int ms=0; ms<4; ++ms)
      fv[ms] = *reinterpret_cast<const f32x4*>(Fr + ms*16 + quad*4);
    // S^T chunk: rows m (4 x 16), col n = lane15
    f32x4 accs[4];
#pragma unroll
    for (int ms=0;ms<4;++ms) accs[ms] = z;
#pragma unroll
    for (int kt=0; kt<2; ++kt){
#pragma unroll
      for (int ms=0; ms<4; ++ms){
        bf16x8 a = *reinterpret_cast<const bf16x8*>(
            &Ks[cur][(ms*16 + lane15)*64 + (((kt*4 + quad) ^ fswz) * 8)]);
        accs[ms] = __builtin_amdgcn_mfma_f32_16x16x32_bf16(a, qf[kt], accs[ms], 0,0,0);
      }
    }
    // fixed-max softmax: p = exp2(score*log2e - F*log2e)
    const bool diag = (mt == nt);
    uint32_t pw[4][2];
#pragma unroll
    for (int ms=0; ms<4; ++ms){
      f32x4 t = accs[ms];
      float p[4];
#pragma unroll
      for (int r=0;r<4;++r){
        float l2 = fmaf(t[r], c1, fv[ms][r]);
        if (diag){
          int ml = ms*16 + quad*4 + r;
          l2 = (ml > n_loc) ? -1e30f : l2;
        }
        p[r] = __builtin_amdgcn_exp2f(l2);
      }
      psum[0]+=p[0]; psum[1]+=p[1]; psum[2]+=p[2]; psum[3]+=p[3];
      pw[ms][0] = pack2(p[0], p[1]);
      pw[ms][1] = pack2(p[2], p[3]);
    }
    // P relayout: C-layout (m=quad*4+r) -> A-fragment (k=quad*8+j) via shuffles
#pragma unroll
    for (int kt=0; kt<2; ++kt){
      union { uint32_t u[4]; bf16x8 v; } pa;
#pragma unroll
      for (int w=0; w<4; ++w){
        int sl = lane15 + 16*((quad&1)*2 + (w>>1));
        uint32_t t0 = (uint32_t)__shfl((int)pw[2*kt  ][w&1], sl);
        uint32_t t1 = (uint32_t)__shfl((int)pw[2*kt+1][w&1], sl);
        pa.u[w] = (quad < 2) ? t0 : t1;
      }
#pragma unroll
      for (int no=0; no<4; ++no){
        int d = no*16 + lane15;
        bf16x8 vb = *reinterpret_cast<const bf16x8*>(
            &Vs[cur][d*64 + (((kt*4 + quad) ^ (d&7)) * 8)]);
        acc_o[no] = __builtin_amdgcn_mfma_f32_16x16x32_bf16(pa.v, vb, acc_o[no], 0,0,0);
      }
    }
  }
  // deferred row-sum reduction; all lanes end with sum for row = lane15
  float s = (psum[0]+psum[1]) + (psum[2]+psum[3]);
  s += __shfl_xor(s, 16);
  s += __shfl_xor(s, 32);
  f32x4 inv;
#pragma unroll
  for (int r=0;r<4;++r)
    inv[r] = __builtin_amdgcn_rcpf(__shfl(s, quad*4 + r));
#pragma unroll
  for (int no=0; no<4; ++no){
#pragma unroll
    for (int r=0;r<4;++r){
      float o = acc_o[no][r] * inv[r];
      int row = nt*64 + wv*16 + quad*4 + r;
      Ob[((size_t)(b*SEQ + row))*D_MODEL + h*64 + no*16 + lane15] = f2bf(o);
    }
  }
}

// ------------------------ NT GEMM, 128x64 tile (O-proj) --------------------
__global__ __launch_bounds__(256) void k_gemm_nt64(
    const u16* __restrict__ A0, const u16* __restrict__ B0,
    float* __restrict__ C, int N, int K)
{
  __shared__ __align__(16) u16 As[128*32];
  __shared__ __align__(16) u16 Bs[64*32];
  const int tid = threadIdx.x, wv = tid>>6, ln = tid&63;
  const int lane15 = ln&15, quad = ln>>4;
  const int wm = wv&1, wn = wv>>1;
  const size_t rowBase = (size_t)blockIdx.y*128, colBase = (size_t)blockIdx.x*64;
  f32x4 acc[4][2];
  f32x4 z = {0.f,0.f,0.f,0.f};
#pragma unroll
  for (int i=0;i<4;++i){ acc[i][0] = z; acc[i][1] = z; }
  const int ktiles = K >> 5;
  const int sRow = ln>>2, sCol = (ln&3)*8;
  for (int kt = 0; kt < ktiles; ++kt) {
    __syncthreads();
#pragma unroll
    for (int c = 0; c < 2; ++c) {
      int chunk = wv*2 + c;
      int r = chunk*16 + sRow;
      const u16* ga = A0 + (rowBase + r)*K + kt*32 + sCol;
      __builtin_amdgcn_global_load_lds(
          (const __attribute__((address_space(1))) void*)ga,
          (__attribute__((address_space(3))) void*)(As + chunk*512), 16, 0, 0);
    }
    {
      int r = wv*16 + sRow;
      const u16* gb = B0 + (colBase + r)*K + kt*32 + sCol;
      __builtin_amdgcn_global_load_lds(
          (const __attribute__((address_space(1))) void*)gb,
          (__attribute__((address_space(3))) void*)(Bs + wv*512), 16, 0, 0);
    }
    __syncthreads();
    bf16x8 af[4], bfb[2];
#pragma unroll
    for (int t=0;t<4;++t)
      af[t]  = *reinterpret_cast<const bf16x8*>(As + (wm*64 + t*16 + lane15)*32 + quad*8);
#pragma unroll
    for (int t=0;t<2;++t)
      bfb[t] = *reinterpret_cast<const bf16x8*>(Bs + (wn*32 + t*16 + lane15)*32 + quad*8);
#pragma unroll
    for (int i=0;i<4;++i)
#pragma unroll
      for (int j=0;j<2;++j)
        acc[i][j] = __builtin_amdgcn_mfma_f32_16x16x32_bf16(af[i], bfb[j], acc[i][j], 0,0,0);
  }
#pragma unroll
  for (int i=0;i<4;++i){
    size_t row = rowBase + wm*64 + i*16 + quad*4;
#pragma unroll
    for (int j=0;j<2;++j){
      size_t col = colBase + wn*32 + j*16 + lane15;
#pragma unroll
      for (int r=0;r<4;++r)
        C[(row+r)*N + col] = acc[i][j][r];
    }
  }
}

// ------------------------------- launcher ----------------------------------
extern "C" void kernel_launch(void* const* d_in, const int* in_sizes, int n_in,
                              void* d_out, int out_size, void* d_ws, size_t ws_size,
                              hipStream_t stream)
{
  (void)in_sizes; (void)n_in; (void)out_size; (void)ws_size;
  const float* X  = (const float*)d_in[0];
  const float* Wq = (const float*)d_in[1];
  const float* Wk = (const float*)d_in[2];
  const float* Wv = (const float*)d_in[3];
  const float* Wo = (const float*)d_in[4];
  const float* gq = (const float*)d_in[5];
  const float* bq = (const float*)d_in[6];
  const float* gk = (const float*)d_in[7];
  const float* bk = (const float*)d_in[8];
  float* out = (float*)d_out;

  char* ws = (char*)d_ws;
  size_t off = 0;
  auto alloc = [&](size_t bytes)->char*{
    char* p = ws + off; off += (bytes + 255) & ~(size_t)255; return p;
  };
  u16* Xhi  = (u16*)alloc((size_t)ROWS*D_MODEL*2);
  u16* Xlo  = (u16*)alloc((size_t)ROWS*D_MODEL*2);
  u16* Wqkh = (u16*)alloc((size_t)2*D_MODEL*D_MODEL*2);  // [Wq;Wk] hi
  u16* Wqkl = (u16*)alloc((size_t)2*D_MODEL*D_MODEL*2);  // [Wq;Wk] lo
  u16* Wvb  = (u16*)alloc((size_t)D_MODEL*D_MODEL*2);
  u16* Wob  = (u16*)alloc((size_t)D_MODEL*D_MODEL*2);
  u16* Qhp  = (u16*)alloc((size_t)BATCH*N_HEADS*SEQ*D_HEAD*2);
  u16* Khp  = (u16*)alloc((size_t)BATCH*N_HEADS*SEQ*D_HEAD*2);
  u16* Q0l  = (u16*)alloc((size_t)BATCH*SEQ*D_HEAD*2);
  u16* K0l  = (u16*)alloc((size_t)BATCH*SEQ*D_HEAD*2);
  u16* Vtp  = (u16*)alloc((size_t)BATCH*N_HEADS*D_HEAD*SEQ*2);
  u16* Obf  = (u16*)alloc((size_t)ROWS*D_MODEL*2);
  float* Dlt = (float*)alloc((size_t)ROWS*128*4);        // head-0 corrections
  float* Seg = (float*)alloc((size_t)BATCH*NSEG*SEQ*4);  // 1 MB
  float* SF  = (float*)alloc((size_t)BATCH*SEQ*SEQ*4);   // 33.5 MB
  float* C32 = SF;    // QK-proj fp32 scratch aliases SF (consumed before s0)

  // Dlt must start at zero (harness poisons ws with 0xAA)
  hipMemsetAsync(Dlt, 0, (size_t)ROWS*128*4, stream);

  // all casts, one launch
  k_cast_all<<<8192, 256, 0, stream>>>(
      X, Xhi, Xlo,
      Wq, Wqkh, Wqkl,
      Wk, Wqkh + (size_t)D_MODEL*D_MODEL, Wqkl + (size_t)D_MODEL*D_MODEL,
      Wv, Wvb, Wo, Wob);

  // qk GEMM + head-0 corr (Dlt) + V^T GEMM, one launch
  k_mega<<<1152, 256, 0, stream>>>(Xhi, Xlo, Wqkh, Wqkl, Wvb, C32, Dlt, Vtp);

  // both LNs + packs (head-0 corrected via Dlt)
  k_ln_pack2<<<ROWS, 256, 0, stream>>>(C32, Dlt, gq, bq, gk, bk, Qhp, Khp, Q0l, K0l);
  // head-0 scores + fused 32-row segment sums; apply (prefix; -F*log2e)
  k_s0<<<dim3(16, 16, BATCH), 256, 0, stream>>>(Qhp, Q0l, Khp, K0l, SF, Seg);
  k_seg_apply<<<dim3(8, NSEG, BATCH), 256, 0, stream>>>(SF, Seg);
  // attention (64-row Q tiles, 4 blocks/CU)
  k_attn<<<dim3(N_HEADS, SEQ/64, BATCH), 256, 0, stream>>>(Qhp, Khp, Vtp, SF, Obf);
  // output projection
  k_gemm_nt64<<<dim3(16, 32), 256, 0, stream>>>(Obf, Wob, out, D_MODEL, D_MODEL);
}

// Round 8
// 291.598 us; speedup vs baseline: 1.1457x; 1.0696x over previous
//
#include <hip/hip_runtime.h>
#include <cstdint>
#include <cstddef>

// ---------------------------------------------------------------------------
// MultiheadSelectiveAttention (B=2, S=2048, D=1024, H=16, dh=64), fp32 in/out.
//   k_cast_all: X,Wq,Wk -> hi/lo bf16; Wv,Wo -> bf16
//   k_mega: corr->Dlt (0-127) | qk GEMM (128-639) | V^T GEMM (640-1151)
//           all BK=64, XOR-swizzled LDS (conflict-free ds_read_b128)
//   k_ln_pack2: LN(Q),LN(K); head-0 cols += Dlt -> bf16 packs (+head0 lo)
//   k_s0: head-0 scores, single-staged 4-tile LDS (64KB), 96 MFMAs/block
//   k_seg_apply: in-place S -> -F*log2e, 32-row segments
//   k_attn: 64-row Q tiles, fixed-max softmax, dbuf DMA staging, register P,
//           F register-prefetched one iteration ahead
//   k_gemm_nt64: out = Obf @ Wo^T (BK=64, swizzled)
// ---------------------------------------------------------------------------

typedef unsigned short u16;
typedef __attribute__((ext_vector_type(8))) __bf16 bf16x8;
typedef __attribute__((ext_vector_type(4))) float f32x4;

#define D_MODEL 1024
#define N_HEADS 16
#define BATCH   2
#define SEQ     2048
#define D_HEAD  64
#define ROWS    (BATCH*SEQ)   /* 4096 */
#define NSEG    64
#define SEGLEN  32
#define LOG2E   1.44269504f

static __device__ __forceinline__ u16 f2bf(float f){
  union { float f; uint32_t u; } v; v.f = f;
  uint32_t r = v.u + 0x7fffu + ((v.u >> 16) & 1u);
  return (u16)(r >> 16);
}
static __device__ __forceinline__ float bf2f(u16 h){
  union { uint32_t u; float f; } v; v.u = ((uint32_t)h) << 16;
  return v.f;
}
static __device__ __forceinline__ uint32_t pack2(float a, float b){
  uint32_t ua = __float_as_uint(a) + 0x8000u;
  uint32_t ub = __float_as_uint(b) + 0x8000u;
  return (ua >> 16) | (ub & 0xffff0000u);
}
#define GLDS(gp, lp) __builtin_amdgcn_global_load_lds( \
    (const __attribute__((address_space(1))) void*)(gp), \
    (__attribute__((address_space(3))) void*)(lp), 16, 0, 0)

// ------------------------- merged cast kernel ------------------------------
__global__ void k_cast_all(const float* __restrict__ X,
                           u16* __restrict__ Xhi, u16* __restrict__ Xlo,
                           const float* __restrict__ Wq,
                           u16* __restrict__ Wqh, u16* __restrict__ Wql,
                           const float* __restrict__ Wk,
                           u16* __restrict__ Wkh, u16* __restrict__ Wkl,
                           const float* __restrict__ Wv, u16* __restrict__ Wvb,
                           const float* __restrict__ Wo, u16* __restrict__ Wob){
  int i = blockIdx.x*256 + threadIdx.x;   // float4 index
  if (i < 1572864){                       // split: X | Wq | Wk
    const float* src; u16 *dh, *dl; int base;
    if (i < 1048576){ src = X;  dh = Xhi; dl = Xlo; base = i; }
    else if (i < 1310720){ src = Wq; dh = Wqh; dl = Wql; base = i - 1048576; }
    else { src = Wk; dh = Wkh; dl = Wkl; base = i - 1310720; }
    float4 v = reinterpret_cast<const float4*>(src)[base];
    float vs[4] = {v.x, v.y, v.z, v.w};
    union { u16 s[4]; uint2 u; } uh, ul;
#pragma unroll
    for (int r=0;r<4;++r){
      uh.s[r] = f2bf(vs[r]);
      ul.s[r] = f2bf(vs[r] - bf2f(uh.s[r]));
    }
    reinterpret_cast<uint2*>(dh)[base] = uh.u;
    reinterpret_cast<uint2*>(dl)[base] = ul.u;
  } else {                                // plain: Wv | Wo
    const float* src; u16* dst; int base;
    if (i < 1835008){ src = Wv; dst = Wvb; base = i - 1572864; }
    else { src = Wo; dst = Wob; base = i - 1835008; }
    float4 v = reinterpret_cast<const float4*>(src)[base];
    float vs[4] = {v.x, v.y, v.z, v.w};
    union { u16 s[4]; uint2 u; } uh;
#pragma unroll
    for (int r=0;r<4;++r) uh.s[r] = f2bf(vs[r]);
    reinterpret_cast<uint2*>(dst)[base] = uh.u;
  }
}

// ---- mega: corr (0-127) | qk (128-639) | vt (640-1151), BK=64 swizzled ----
__global__ __launch_bounds__(256) void k_mega(
    const u16* __restrict__ Xhi, const u16* __restrict__ Xlo,
    const u16* __restrict__ Wh,  const u16* __restrict__ Wl,
    const u16* __restrict__ Wvb,
    float* __restrict__ C, float* __restrict__ Dlt, u16* __restrict__ Vt)
{
  __shared__ __align__(16) u16 smem[16384];   // 32 KB
  const int bid = blockIdx.x;
  const int tid = threadIdx.x, wv = tid>>6, ln = tid&63;
  const int lane15 = ln&15, quad = ln>>4;
  const int wm = wv&1, wn = wv>>1;
  const int g = ln&7, sr = ln>>3;           // staging lane coords
  const int fs = lane15 & 7;                // fragment swizzle key
  f32x4 z = {0.f,0.f,0.f,0.f};
  u16* As = smem;                           // 128x64 (8192 u16)
  u16* Bs = smem + 8192;

  if (bid < 128){
    // ---- head-0 correction: Dlt += Xhi@Wlo^T or Xlo@Whi^T (per pass) ------
    const int cx = bid & 1;             // Q / K col-group
    const int cy = (bid >> 1) & 31;     // row tile
    const int cz = bid >> 6;            // pass
    const size_t rowBase = (size_t)cy*128;
    const size_t wbase = cx ? (size_t)1024*1024 : 0;
    const u16* Ap = cz ? Xlo : Xhi;
    const u16* Bp = (cz ? Wh : Wl) + wbase;
    f32x4 acc[4][2];
#pragma unroll
    for (int i=0;i<4;++i){ acc[i][0] = z; acc[i][1] = z; }
    for (int kt = 0; kt < 16; ++kt) {
      __syncthreads();
#pragma unroll
      for (int c = 0; c < 4; ++c) {
        int chunk = wv*4 + c, r = chunk*8 + sr;
        GLDS(Ap + (rowBase + r)*1024 + kt*64 + (g^sr)*8, As + chunk*512);
      }
#pragma unroll
      for (int c = 0; c < 2; ++c) {
        int chunk = wv*2 + c, r = chunk*8 + sr;
        GLDS(Bp + (size_t)r*1024 + kt*64 + (g^sr)*8, Bs + chunk*512);
      }
      __syncthreads();
#pragma unroll
      for (int k2=0;k2<2;++k2){
        bf16x8 af[4], bfb[2];
#pragma unroll
        for (int t=0;t<4;++t)
          af[t]  = *reinterpret_cast<const bf16x8*>(As + (wm*64 + t*16 + lane15)*64 + (((k2*4+quad)^fs)*8));
#pragma unroll
        for (int t=0;t<2;++t)
          bfb[t] = *reinterpret_cast<const bf16x8*>(Bs + (wn*32 + t*16 + lane15)*64 + (((k2*4+quad)^fs)*8));
#pragma unroll
        for (int i=0;i<4;++i)
#pragma unroll
          for (int j=0;j<2;++j)
            acc[i][j] = __builtin_amdgcn_mfma_f32_16x16x32_bf16(af[i], bfb[j], acc[i][j], 0,0,0);
      }
    }
#pragma unroll
    for (int i=0;i<4;++i){
      size_t row = rowBase + wm*64 + i*16 + quad*4;
#pragma unroll
      for (int j=0;j<2;++j){
        size_t col = (size_t)cx*64 + wn*32 + j*16 + lane15;
#pragma unroll
        for (int r=0;r<4;++r)
          atomicAdd(&Dlt[(row+r)*128 + col], acc[i][j][r]);
      }
    }
  } else if (bid < 640){
    // ---------------- QK projection: 128x128 tile, 1-pass ------------------
    const int idx = bid - 128;
    const size_t rowBase = (size_t)(idx>>4)*128, colBase = (size_t)(idx&15)*128;
    f32x4 acc[4][4];
#pragma unroll
    for (int i=0;i<4;++i)
#pragma unroll
      for (int j=0;j<4;++j) acc[i][j] = z;
    for (int kt = 0; kt < 16; ++kt) {
      __syncthreads();
#pragma unroll
      for (int c = 0; c < 4; ++c) {
        int chunk = wv*4 + c, r = chunk*8 + sr;
        GLDS(Xhi + (rowBase + r)*1024 + kt*64 + (g^sr)*8, As + chunk*512);
        GLDS(Wh  + (colBase + r)*1024 + kt*64 + (g^sr)*8, Bs + chunk*512);
      }
      __syncthreads();
#pragma unroll
      for (int k2=0;k2<2;++k2){
        bf16x8 af[4], bfb[4];
#pragma unroll
        for (int t=0;t<4;++t){
          af[t]  = *reinterpret_cast<const bf16x8*>(As + (wm*64 + t*16 + lane15)*64 + (((k2*4+quad)^fs)*8));
          bfb[t] = *reinterpret_cast<const bf16x8*>(Bs + (wn*64 + t*16 + lane15)*64 + (((k2*4+quad)^fs)*8));
        }
#pragma unroll
        for (int i=0;i<4;++i)
#pragma unroll
          for (int j=0;j<4;++j)
            acc[i][j] = __builtin_amdgcn_mfma_f32_16x16x32_bf16(af[i], bfb[j], acc[i][j], 0,0,0);
      }
    }
#pragma unroll
    for (int i=0;i<4;++i){
      size_t row = rowBase + wm*64 + i*16 + quad*4;
#pragma unroll
      for (int j=0;j<4;++j){
        size_t col = colBase + wn*64 + j*16 + lane15;
#pragma unroll
        for (int r=0;r<4;++r)
          C[(row+r)*2048 + col] = acc[i][j][r];
      }
    }
  } else {
    // ------- V projection with fused V^T bf16 epilogue (LDS transpose) -----
    const int idx = bid - 640;
    const int bx = idx & 15, by = idx >> 4;
    const size_t rowBase = (size_t)by*128, colBase = (size_t)bx*64;
    f32x4 acc[4][2];
#pragma unroll
    for (int i=0;i<4;++i){ acc[i][0] = z; acc[i][1] = z; }
    for (int kt = 0; kt < 16; ++kt) {
      __syncthreads();
#pragma unroll
      for (int c = 0; c < 4; ++c) {
        int chunk = wv*4 + c, r = chunk*8 + sr;
        GLDS(Xhi + (rowBase + r)*1024 + kt*64 + (g^sr)*8, As + chunk*512);
      }
#pragma unroll
      for (int c = 0; c < 2; ++c) {
        int chunk = wv*2 + c, r = chunk*8 + sr;
        GLDS(Wvb + (colBase + r)*1024 + kt*64 + (g^sr)*8, Bs + chunk*512);
      }
      __syncthreads();
#pragma unroll
      for (int k2=0;k2<2;++k2){
        bf16x8 af[4], bfb[2];
#pragma unroll
        for (int t=0;t<4;++t)
          af[t]  = *reinterpret_cast<const bf16x8*>(As + (wm*64 + t*16 + lane15)*64 + (((k2*4+quad)^fs)*8));
#pragma unroll
        for (int t=0;t<2;++t)
          bfb[t] = *reinterpret_cast<const bf16x8*>(Bs + (wn*32 + t*16 + lane15)*64 + (((k2*4+quad)^fs)*8));
#pragma unroll
        for (int i=0;i<4;++i)
#pragma unroll
          for (int j=0;j<2;++j)
            acc[i][j] = __builtin_amdgcn_mfma_f32_16x16x32_bf16(af[i], bfb[j], acc[i][j], 0,0,0);
      }
    }
    // transpose epilogue: stage bf16 tile as [d 64][n 128] (stride 136)
    __syncthreads();
#pragma unroll
    for (int i=0;i<4;++i){
      int nl = wm*64 + i*16 + quad*4;
#pragma unroll
      for (int j=0;j<2;++j){
        int dl = wn*32 + j*16 + lane15;
#pragma unroll
        for (int r=0;r<4;++r)
          smem[dl*136 + nl + r] = f2bf(acc[i][j][r]);
      }
    }
    __syncthreads();
    const int b = by >> 4;
    const int n0 = (by & 15) * 128;
    const int bh = b*N_HEADS + bx;
    const int d = tid >> 2, seg = tid & 3;
    u16* dst = Vt + ((size_t)(bh*64 + d))*SEQ + n0 + seg*32;
    const u16* srcl = smem + d*136 + seg*32;
#pragma unroll
    for (int k=0;k<4;++k)
      *reinterpret_cast<uint4*>(dst + k*8) = *reinterpret_cast<const uint4*>(srcl + k*8);
  }
}

// --------- merged LN for Q and K + bf16 head packs (+ head0 corr) ----------
__global__ __launch_bounds__(256) void k_ln_pack2(
    const float* __restrict__ C, const float* __restrict__ Dlt,
    const float* __restrict__ gq, const float* __restrict__ bq,
    const float* __restrict__ gk, const float* __restrict__ bk,
    u16* __restrict__ Qh, u16* __restrict__ Kh,
    u16* __restrict__ Q0l, u16* __restrict__ K0l)
{
  const int row = blockIdx.x;
  const int tid = threadIdx.x;
  const float* cr = C + (size_t)row*2048;
  float4 vq = reinterpret_cast<const float4*>(cr)[tid];
  float4 vk = reinterpret_cast<const float4*>(cr)[256 + tid];
  const int h = tid >> 4;
  if (h == 0){
    float4 dq = reinterpret_cast<const float4*>(Dlt + (size_t)row*128)[tid&15];
    vq.x+=dq.x; vq.y+=dq.y; vq.z+=dq.z; vq.w+=dq.w;
    float4 dk = reinterpret_cast<const float4*>(Dlt + (size_t)row*128 + 64)[tid&15];
    vk.x+=dk.x; vk.y+=dk.y; vk.z+=dk.z; vk.w+=dk.w;
  }
  float sq  = vq.x+vq.y+vq.z+vq.w;
  float s2q = vq.x*vq.x+vq.y*vq.y+vq.z*vq.z+vq.w*vq.w;
  float sk  = vk.x+vk.y+vk.z+vk.w;
  float s2k = vk.x*vk.x+vk.y*vk.y+vk.z*vk.z+vk.w*vk.w;
#pragma unroll
  for (int o=32;o;o>>=1){
    sq += __shfl_xor(sq,o);  s2q += __shfl_xor(s2q,o);
    sk += __shfl_xor(sk,o);  s2k += __shfl_xor(s2k,o);
  }
  __shared__ float red[4][4];
  if ((tid&63)==0){
    red[tid>>6][0]=sq; red[tid>>6][1]=s2q; red[tid>>6][2]=sk; red[tid>>6][3]=s2k;
  }
  __syncthreads();
  sq  = red[0][0]+red[1][0]+red[2][0]+red[3][0];
  s2q = red[0][1]+red[1][1]+red[2][1]+red[3][1];
  sk  = red[0][2]+red[1][2]+red[2][2]+red[3][2];
  s2k = red[0][3]+red[1][3]+red[2][3]+red[3][3];
  const float muq = sq*(1.f/D_MODEL);
  const float rsq = rsqrtf(s2q*(1.f/D_MODEL) - muq*muq + 1e-5f);
  const float muk = sk*(1.f/D_MODEL);
  const float rsk = rsqrtf(s2k*(1.f/D_MODEL) - muk*muk + 1e-5f);
  const int b = row >> 11, n = row & (SEQ-1);
  const int d0 = (tid & 15)*4;
  float4 gqv = reinterpret_cast<const float4*>(gq)[tid];
  float4 bqv = reinterpret_cast<const float4*>(bq)[tid];
  float4 gkv = reinterpret_cast<const float4*>(gk)[tid];
  float4 bkv = reinterpret_cast<const float4*>(bk)[tid];
  float xq[4] = {vq.x,vq.y,vq.z,vq.w}, xk[4] = {vk.x,vk.y,vk.z,vk.w};
  float gQ[4] = {gqv.x,gqv.y,gqv.z,gqv.w}, bQ[4] = {bqv.x,bqv.y,bqv.z,bqv.w};
  float gK[4] = {gkv.x,gkv.y,gkv.z,gkv.w}, bK[4] = {bkv.x,bkv.y,bkv.z,bkv.w};
  union { u16 s[4]; uint2 u; } qh, ql, kh, kl;
#pragma unroll
  for (int r=0;r<4;++r){
    float yq = (xq[r]-muq)*rsq*gQ[r] + bQ[r];
    qh.s[r] = f2bf(yq);
    ql.s[r] = f2bf(yq - bf2f(qh.s[r]));
    float yk = (xk[r]-muk)*rsk*gK[r] + bK[r];
    kh.s[r] = f2bf(yk);
    kl.s[r] = f2bf(yk - bf2f(kh.s[r]));
  }
  size_t dst = (((size_t)(b*N_HEADS + h))*SEQ + n)*D_HEAD + d0;
  *reinterpret_cast<uint2*>(Qh + dst) = qh.u;
  *reinterpret_cast<uint2*>(Kh + dst) = kh.u;
  if (h == 0){
    size_t dl = ((size_t)b*SEQ + n)*D_HEAD + d0;
    *reinterpret_cast<uint2*>(Q0l + dl) = ql.u;
    *reinterpret_cast<uint2*>(K0l + dl) = kl.u;
  }
}

// ------ head-0 scores, single-staged 4-tile LDS + 32-row segment sums ------
__global__ __launch_bounds__(256) void k_s0(
    const u16* Qh, const u16* Q0l, const u16* Kh, const u16* K0l,
    float* __restrict__ S0, float* __restrict__ seg)
{
  const int b = blockIdx.z;
  const int bm = blockIdx.y;  // j (query-row) 128-tile -> segments 4bm..4bm+3
  const int bn = blockIdx.x;  // m (key-col) tile
  const int tid = threadIdx.x;
  if (bn > bm){               // above diagonal: S never read there; seg = 0
    for (int t = tid; t < 512; t += 256)
      seg[((size_t)b*NSEG + bm*4 + (t>>7))*SEQ + bn*128 + (t&127)] = 0.f;
    return;
  }
  float* Sb = S0 + (size_t)b*SEQ*SEQ;
  __shared__ __align__(16) u16 smem[4*8192];   // Qhi|Qlo|Khi|Klo, 64 KB
  const int wv = tid>>6, ln = tid&63;
  const int lane15 = ln&15, quad = ln>>4;
  const int wm = wv&1, wn = wv>>1;
  const int g = ln&7, sr = ln>>3;
  const int fs = lane15 & 7;
  const size_t rowBase = (size_t)bm*128, colBase = (size_t)bn*128;
  const u16* srcs[4] = {
    Qh  + ((size_t)b*N_HEADS*SEQ + rowBase)*D_HEAD,   // head-0 Q hi
    Q0l + ((size_t)b*SEQ + rowBase)*D_HEAD,
    Kh  + ((size_t)b*N_HEADS*SEQ + colBase)*D_HEAD,   // head-0 K hi
    K0l + ((size_t)b*SEQ + colBase)*D_HEAD };
#pragma unroll
  for (int t=0;t<4;++t){
#pragma unroll
    for (int c=0;c<4;++c){
      int chunk = wv*4 + c, r = chunk*8 + sr;
      GLDS(srcs[t] + (size_t)r*64 + (g^sr)*8, smem + t*8192 + chunk*512);
    }
  }
  __syncthreads();
  f32x4 acc[4][4];
  f32x4 z = {0.f,0.f,0.f,0.f};
#pragma unroll
  for (int i=0;i<4;++i)
#pragma unroll
    for (int j=0;j<4;++j) acc[i][j] = z;
  const int Aidx[3] = {0, 0, 1};    // Qhi,Qhi,Qlo
  const int Bidx[3] = {2, 3, 2};    // Khi,Klo,Khi
#pragma unroll
  for (int p = 0; p < 3; ++p){
    const u16* At = smem + Aidx[p]*8192;
    const u16* Bt = smem + Bidx[p]*8192;
#pragma unroll
    for (int k2=0;k2<2;++k2){
      bf16x8 af[4], bfb[4];
#pragma unroll
      for (int t=0;t<4;++t){
        af[t]  = *reinterpret_cast<const bf16x8*>(At + (wm*64 + t*16 + lane15)*64 + (((k2*4+quad)^fs)*8));
        bfb[t] = *reinterpret_cast<const bf16x8*>(Bt + (wn*64 + t*16 + lane15)*64 + (((k2*4+quad)^fs)*8));
      }
#pragma unroll
      for (int i=0;i<4;++i)
#pragma unroll
        for (int j=0;j<4;++j)
          acc[i][j] = __builtin_amdgcn_mfma_f32_16x16x32_bf16(af[i], bfb[j], acc[i][j], 0,0,0);
    }
  }
  float csum[2][4] = {{0.f,0.f,0.f,0.f},{0.f,0.f,0.f,0.f}};
#pragma unroll
  for (int i=0;i<4;++i){
#pragma unroll
    for (int j=0;j<4;++j){
#pragma unroll
      for (int r=0;r<4;++r){
        int jg = (int)rowBase + wm*64 + i*16 + quad*4 + r;
        int mg = (int)colBase + wn*64 + j*16 + lane15;
        float l = acc[i][j][r]*0.125f;
        float s = (mg >= 1 && mg < jg) ? fmaxf(l, 0.f) : 0.f;
        Sb[(size_t)jg*SEQ + mg] = s;
        csum[i>>1][j] += s;
      }
    }
  }
  __syncthreads();                 // tiles consumed; reuse LDS for cs
  float* cs = (float*)smem;        // [4][128]
#pragma unroll
  for (int h2=0;h2<2;++h2){
#pragma unroll
    for (int j=0;j<4;++j){
      float v = csum[h2][j];
      v += __shfl_xor(v, 16);
      v += __shfl_xor(v, 32);
      if (ln < 16) cs[(wm*2 + h2)*128 + wn*64 + j*16 + ln] = v;
    }
  }
  __syncthreads();
  for (int t = tid; t < 512; t += 256)
    seg[((size_t)b*NSEG + bm*4 + (t>>7))*SEQ + bn*128 + (t&127)] = cs[t];
}

// --- in place: S -> -F*log2e; 32-row segments; prefix from seg sums --------
__global__ void k_seg_apply(float* __restrict__ SF, const float* __restrict__ seg){
  int m = blockIdx.x*256 + threadIdx.x;
  int s = blockIdx.y, b = blockIdx.z;
  const float* sb = seg + (size_t)b*NSEG*SEQ;
  float run = 0.f;
  for (int t=0; t<s; ++t) run += sb[(size_t)t*SEQ + m];   // independent loads
  float* Sb = SF + (size_t)b*SEQ*SEQ;
  const int j0 = s*SEGLEN;
#pragma unroll 8
  for (int i=0;i<SEGLEN;++i){
    size_t idx = (size_t)(j0 + i)*SEQ + m;
    float t = Sb[idx];
    Sb[idx] = -run*LOG2E;
    run += (j0 + i > m) ? t : 0.f;
  }
}

// ------------- flash attention, fixed-max softmax, double-buffered ---------
// 64-row Q tiles, 4 blocks/CU; F register-prefetched one iteration ahead.
__global__ __launch_bounds__(256, 4) void k_attn(
    const u16* __restrict__ Qh, const u16* __restrict__ Kh,
    const u16* __restrict__ Vt, const float* __restrict__ F,
    u16* __restrict__ Ob)
{
  __shared__ __align__(16) u16 Ks[2][64*64];
  __shared__ __align__(16) u16 Vs[2][64*64];
  const int h = blockIdx.x, b = blockIdx.z;
  const int nt = b ? (int)(gridDim.y - 1 - blockIdx.y) : (int)blockIdx.y;
  const int tid = threadIdx.x, wv = tid>>6, ln = tid&63;
  const int lane15 = ln&15, quad = ln>>4;
  const u16* Qbh = Qh + ((size_t)(b*N_HEADS + h))*SEQ*D_HEAD;
  const u16* Kbh = Kh + ((size_t)(b*N_HEADS + h))*SEQ*D_HEAD;
  const u16* Vbh = Vt + ((size_t)(b*N_HEADS + h))*D_HEAD*SEQ;
  const int n_loc = wv*16 + lane15;
  const int n_g = nt*64 + n_loc;
  const float* Frow = F + (size_t)b*SEQ*SEQ + (size_t)n_g*SEQ;
  const int swz = (ln&7) ^ ((ln>>3)&7);
  const int fswz = lane15 & 7;
  const int srow = ln>>3;

  bf16x8 qf[2];
#pragma unroll
  for (int kt=0; kt<2; ++kt)
    qf[kt] = *reinterpret_cast<const bf16x8*>(Qbh + (size_t)n_g*D_HEAD + kt*32 + quad*8);

  f32x4 z = {0.f,0.f,0.f,0.f};
  f32x4 psum = z;
  f32x4 acc_o[4];
#pragma unroll
  for (int no=0;no<4;++no) acc_o[no] = z;

  auto stage = [&](int mt, int buf){
#pragma unroll
    for (int c=0;c<2;++c){
      int chunk = wv*2 + c;
      int r = chunk*8 + srow;
      GLDS(Kbh + (size_t)(mt*64 + r)*D_HEAD + swz*8, &Ks[buf][chunk*512]);
      GLDS(Vbh + (size_t)r*SEQ + mt*64 + swz*8,      &Vs[buf][chunk*512]);
    }
  };
  stage(0, 0);
  // preload F for chunk 0 (already stored as -F*log2e)
  f32x4 fvn[4];
#pragma unroll
  for (int ms=0; ms<4; ++ms)
    fvn[ms] = *reinterpret_cast<const f32x4*>(Frow + ms*16 + quad*4);
  const float c1 = 0.125f*LOG2E;

  for (int mt = 0; mt <= nt; ++mt) {
    const int cur = mt & 1;
    __syncthreads();                    // drain: buf[cur] ready
    if (mt < nt) stage(mt+1, 1-cur);    // prefetch next K/V chunk
    f32x4 fv[4];
#pragma unroll
    for (int ms=0; ms<4; ++ms) fv[ms] = fvn[ms];
    if (mt < nt){                       // prefetch next F chunk into registers
      const float* Fr1 = Frow + (mt+1)*64;
#pragma unroll
      for (int ms=0; ms<4; ++ms)
        fvn[ms] = *reinterpret_cast<const f32x4*>(Fr1 + ms*16 + quad*4);
    }
    // S^T chunk: rows m (4 x 16), col n = lane15
    f32x4 accs[4];
#pragma unroll
    for (int ms=0;ms<4;++ms) accs[ms] = z;
#pragma unroll
    for (int kt=0; kt<2; ++kt){
#pragma unroll
      for (int ms=0; ms<4; ++ms){
        bf16x8 a = *reinterpret_cast<const bf16x8*>(
            &Ks[cur][(ms*16 + lane15)*64 + (((kt*4 + quad) ^ fswz) * 8)]);
        accs[ms] = __builtin_amdgcn_mfma_f32_16x16x32_bf16(a, qf[kt], accs[ms], 0,0,0);
      }
    }
    // fixed-max softmax: p = exp2(score*log2e - F*log2e)
    const bool diag = (mt == nt);
    uint32_t pw[4][2];
#pragma unroll
    for (int ms=0; ms<4; ++ms){
      f32x4 t = accs[ms];
      float p[4];
#pragma unroll
      for (int r=0;r<4;++r){
        float l2 = fmaf(t[r], c1, fv[ms][r]);
        if (diag){
          int ml = ms*16 + quad*4 + r;
          l2 = (ml > n_loc) ? -1e30f : l2;
        }
        p[r] = __builtin_amdgcn_exp2f(l2);
      }
      psum[0]+=p[0]; psum[1]+=p[1]; psum[2]+=p[2]; psum[3]+=p[3];
      pw[ms][0] = pack2(p[0], p[1]);
      pw[ms][1] = pack2(p[2], p[3]);
    }
    // P relayout: C-layout (m=quad*4+r) -> A-fragment (k=quad*8+j) via shuffles
#pragma unroll
    for (int kt=0; kt<2; ++kt){
      union { uint32_t u[4]; bf16x8 v; } pa;
#pragma unroll
      for (int w=0; w<4; ++w){
        int sl = lane15 + 16*((quad&1)*2 + (w>>1));
        uint32_t t0 = (uint32_t)__shfl((int)pw[2*kt  ][w&1], sl);
        uint32_t t1 = (uint32_t)__shfl((int)pw[2*kt+1][w&1], sl);
        pa.u[w] = (quad < 2) ? t0 : t1;
      }
#pragma unroll
      for (int no=0; no<4; ++no){
        int d = no*16 + lane15;
        bf16x8 vb = *reinterpret_cast<const bf16x8*>(
            &Vs[cur][d*64 + (((kt*4 + quad) ^ (d&7)) * 8)]);
        acc_o[no] = __builtin_amdgcn_mfma_f32_16x16x32_bf16(pa.v, vb, acc_o[no], 0,0,0);
      }
    }
  }
  float s = (psum[0]+psum[1]) + (psum[2]+psum[3]);
  s += __shfl_xor(s, 16);
  s += __shfl_xor(s, 32);
  f32x4 inv;
#pragma unroll
  for (int r=0;r<4;++r)
    inv[r] = __builtin_amdgcn_rcpf(__shfl(s, quad*4 + r));
#pragma unroll
  for (int no=0; no<4; ++no){
#pragma unroll
    for (int r=0;r<4;++r){
      float o = acc_o[no][r] * inv[r];
      int row = nt*64 + wv*16 + quad*4 + r;
      Ob[((size_t)(b*SEQ + row))*D_MODEL + h*64 + no*16 + lane15] = f2bf(o);
    }
  }
}

// ------------- NT GEMM, 128x64 tile, BK=64 swizzled (O-proj) ---------------
__global__ __launch_bounds__(256) void k_gemm_nt64(
    const u16* __restrict__ A0, const u16* __restrict__ B0,
    float* __restrict__ C, int N, int K)
{
  __shared__ __align__(16) u16 As[8192];   // 128x64
  __shared__ __align__(16) u16 Bs[4096];   // 64x64
  const int tid = threadIdx.x, wv = tid>>6, ln = tid&63;
  const int lane15 = ln&15, quad = ln>>4;
  const int wm = wv&1, wn = wv>>1;
  const int g = ln&7, sr = ln>>3;
  const int fs = lane15 & 7;
  const size_t rowBase = (size_t)blockIdx.y*128, colBase = (size_t)blockIdx.x*64;
  f32x4 acc[4][2];
  f32x4 z = {0.f,0.f,0.f,0.f};
#pragma unroll
  for (int i=0;i<4;++i){ acc[i][0] = z; acc[i][1] = z; }
  const int ktiles = K >> 6;
  for (int kt = 0; kt < ktiles; ++kt) {
    __syncthreads();
#pragma unroll
    for (int c = 0; c < 4; ++c) {
      int chunk = wv*4 + c, r = chunk*8 + sr;
      GLDS(A0 + (rowBase + r)*K + kt*64 + (g^sr)*8, As + chunk*512);
    }
#pragma unroll
    for (int c = 0; c < 2; ++c) {
      int chunk = wv*2 + c, r = chunk*8 + sr;
      GLDS(B0 + (colBase + r)*K + kt*64 + (g^sr)*8, Bs + chunk*512);
    }
    __syncthreads();
#pragma unroll
    for (int k2=0;k2<2;++k2){
      bf16x8 af[4], bfb[2];
#pragma unroll
      for (int t=0;t<4;++t)
        af[t]  = *reinterpret_cast<const bf16x8*>(As + (wm*64 + t*16 + lane15)*64 + (((k2*4+quad)^fs)*8));
#pragma unroll
      for (int t=0;t<2;++t)
        bfb[t] = *reinterpret_cast<const bf16x8*>(Bs + (wn*32 + t*16 + lane15)*64 + (((k2*4+quad)^fs)*8));
#pragma unroll
      for (int i=0;i<4;++i)
#pragma unroll
        for (int j=0;j<2;++j)
          acc[i][j] = __builtin_amdgcn_mfma_f32_16x16x32_bf16(af[i], bfb[j], acc[i][j], 0,0,0);
    }
  }
#pragma unroll
  for (int i=0;i<4;++i){
    size_t row = rowBase + wm*64 + i*16 + quad*4;
#pragma unroll
    for (int j=0;j<2;++j){
      size_t col = colBase + wn*32 + j*16 + lane15;
#pragma unroll
      for (int r=0;r<4;++r)
        C[(row+r)*N + col] = acc[i][j][r];
    }
  }
}

// ------------------------------- launcher ----------------------------------
extern "C" void kernel_launch(void* const* d_in, const int* in_sizes, int n_in,
                              void* d_out, int out_size, void* d_ws, size_t ws_size,
                              hipStream_t stream)
{
  (void)in_sizes; (void)n_in; (void)out_size; (void)ws_size;
  const float* X  = (const float*)d_in[0];
  const float* Wq = (const float*)d_in[1];
  const float* Wk = (const float*)d_in[2];
  const float* Wv = (const float*)d_in[3];
  const float* Wo = (const float*)d_in[4];
  const float* gq = (const float*)d_in[5];
  const float* bq = (const float*)d_in[6];
  const float* gk = (const float*)d_in[7];
  const float* bk = (const float*)d_in[8];
  float* out = (float*)d_out;

  char* ws = (char*)d_ws;
  size_t off = 0;
  auto alloc = [&](size_t bytes)->char*{
    char* p = ws + off; off += (bytes + 255) & ~(size_t)255; return p;
  };
  u16* Xhi  = (u16*)alloc((size_t)ROWS*D_MODEL*2);
  u16* Xlo  = (u16*)alloc((size_t)ROWS*D_MODEL*2);
  u16* Wqkh = (u16*)alloc((size_t)2*D_MODEL*D_MODEL*2);  // [Wq;Wk] hi
  u16* Wqkl = (u16*)alloc((size_t)2*D_MODEL*D_MODEL*2);  // [Wq;Wk] lo
  u16* Wvb  = (u16*)alloc((size_t)D_MODEL*D_MODEL*2);
  u16* Wob  = (u16*)alloc((size_t)D_MODEL*D_MODEL*2);
  u16* Qhp  = (u16*)alloc((size_t)BATCH*N_HEADS*SEQ*D_HEAD*2);
  u16* Khp  = (u16*)alloc((size_t)BATCH*N_HEADS*SEQ*D_HEAD*2);
  u16* Q0l  = (u16*)alloc((size_t)BATCH*SEQ*D_HEAD*2);
  u16* K0l  = (u16*)alloc((size_t)BATCH*SEQ*D_HEAD*2);
  u16* Vtp  = (u16*)alloc((size_t)BATCH*N_HEADS*D_HEAD*SEQ*2);
  u16* Obf  = (u16*)alloc((size_t)ROWS*D_MODEL*2);
  float* Dlt = (float*)alloc((size_t)ROWS*128*4);        // head-0 corrections
  float* Seg = (float*)alloc((size_t)BATCH*NSEG*SEQ*4);  // 1 MB
  float* SF  = (float*)alloc((size_t)BATCH*SEQ*SEQ*4);   // 33.5 MB
  float* C32 = SF;    // QK-proj fp32 scratch aliases SF (consumed before s0)

  hipMemsetAsync(Dlt, 0, (size_t)ROWS*128*4, stream);

  k_cast_all<<<8192, 256, 0, stream>>>(
      X, Xhi, Xlo,
      Wq, Wqkh, Wqkl,
      Wk, Wqkh + (size_t)D_MODEL*D_MODEL, Wqkl + (size_t)D_MODEL*D_MODEL,
      Wv, Wvb, Wo, Wob);
  k_mega<<<1152, 256, 0, stream>>>(Xhi, Xlo, Wqkh, Wqkl, Wvb, C32, Dlt, Vtp);
  k_ln_pack2<<<ROWS, 256, 0, stream>>>(C32, Dlt, gq, bq, gk, bk, Qhp, Khp, Q0l, K0l);
  k_s0<<<dim3(16, 16, BATCH), 256, 0, stream>>>(Qhp, Q0l, Khp, K0l, SF, Seg);
  k_seg_apply<<<dim3(8, NSEG, BATCH), 256, 0, stream>>>(SF, Seg);
  k_attn<<<dim3(N_HEADS, SEQ/64, BATCH), 256, 0, stream>>>(Qhp, Khp, Vtp, SF, Obf);
  k_gemm_nt64<<<dim3(16, 32), 256, 0, stream>>>(Obf, Wob, out, D_MODEL, D_MODEL);
}